// Round 6
// baseline (2451.600 us; speedup 1.0000x reference)
//
#include <hip/hip_runtime.h>
#include <hip/hip_bf16.h>

// DimeNet++ forward, f32: 64-row tiles, 4x8 reg tile, coalesced W loads.
namespace {
constexpr int E     = 120000;
constexpr int T     = 800000;
constexpr int NN    = 12000;
constexpr int H     = 128;
constexpr int INTD  = 64;
constexpr int BE    = 8;
constexpr int R     = 6;
constexpr int SR    = 42;
constexpr int OE    = 256;
constexpr float CUTOFF = 5.0f;
}

__device__ __forceinline__ float silu_f(float x) { return x / (1.0f + __expf(-x)); }
__device__ __forceinline__ float4 silu4(float4 v) {
    return make_float4(silu_f(v.x), silu_f(v.y), silu_f(v.z), silu_f(v.w));
}
__device__ __forceinline__ float4 add4(float4 a, float4 b) {
    return make_float4(a.x + b.x, a.y + b.y, a.z + b.z, a.w + b.w);
}
__device__ __forceinline__ float4 mul4(float4 a, float4 b) {
    return make_float4(a.x * b.x, a.y * b.y, a.z * b.z, a.w * b.w);
}
__device__ __forceinline__ void fma4(float4& a, float s, const float4 w) {
    a.x = fmaf(s, w.x, a.x); a.y = fmaf(s, w.y, a.y);
    a.z = fmaf(s, w.z, a.z); a.w = fmaf(s, w.w, a.w);
}
__device__ __forceinline__ float4 f4z() { return make_float4(0.f, 0.f, 0.f, 0.f); }

// 4 rows x 8 cols per-thread GEMM from LDS tile B4 (row stride 33 float4).
// cg=tid&15 (cols cg*8..+7), rq=tid>>4 (rows rq*4..+3). Uniform k4:
// W loads are wave-coalesced (512B region), LDS reads are broadcasts.
template<int K4, int WS4>
__device__ __forceinline__ void mm48(const float4* __restrict__ B4,
                                     const float4* __restrict__ W4,
                                     int cg, int rq, float4 acc[4][2])
{
    #pragma unroll 4
    for (int k4 = 0; k4 < K4; ++k4) {
        const float4 w0a = W4[(k4*4+0)*WS4 + cg*2], w0b = W4[(k4*4+0)*WS4 + cg*2+1];
        const float4 w1a = W4[(k4*4+1)*WS4 + cg*2], w1b = W4[(k4*4+1)*WS4 + cg*2+1];
        const float4 w2a = W4[(k4*4+2)*WS4 + cg*2], w2b = W4[(k4*4+2)*WS4 + cg*2+1];
        const float4 w3a = W4[(k4*4+3)*WS4 + cg*2], w3b = W4[(k4*4+3)*WS4 + cg*2+1];
        #pragma unroll
        for (int rr = 0; rr < 4; ++rr) {
            const float4 a = B4[(rq*4+rr)*33 + k4];
            fma4(acc[rr][0], a.x, w0a); fma4(acc[rr][1], a.x, w0b);
            fma4(acc[rr][0], a.y, w1a); fma4(acc[rr][1], a.y, w1b);
            fma4(acc[rr][0], a.z, w2a); fma4(acc[rr][1], a.z, w2b);
            fma4(acc[rr][0], a.w, w3a); fma4(acc[rr][1], a.w, w3b);
        }
    }
}

__device__ __forceinline__ void z48(float4 acc[4][2]) {
    #pragma unroll
    for (int rr = 0; rr < 4; ++rr) { acc[rr][0] = f4z(); acc[rr][1] = f4z(); }
}
__device__ __forceinline__ void bias48(float4 acc[4][2], const float* bias, int cg) {
    const float4 b0 = reinterpret_cast<const float4*>(bias)[cg*2];
    const float4 b1 = reinterpret_cast<const float4*>(bias)[cg*2+1];
    #pragma unroll
    for (int rr = 0; rr < 4; ++rr) { acc[rr][0] = b0; acc[rr][1] = b1; }
}
// barrier; write v into B4; barrier
__device__ __forceinline__ void wr48(float4* B4, const float4 v[4][2], int cg, int rq) {
    __syncthreads();
    #pragma unroll
    for (int rr = 0; rr < 4; ++rr) {
        B4[(rq*4+rr)*33 + cg*2]     = v[rr][0];
        B4[(rq*4+rr)*33 + cg*2 + 1] = v[rr][1];
    }
    __syncthreads();
}

// ---------------------------------------------------------------------------
// rbf[E,6]
// ---------------------------------------------------------------------------
__global__ void k_rbf(const float* __restrict__ dist, const float* __restrict__ freq,
                      float* __restrict__ rbf) {
    int e = blockIdx.x * blockDim.x + threadIdx.x;
    if (e >= E) return;
    float d  = dist[e] * (1.0f / CUTOFF);
    float d2 = d * d;
    float d5 = d2 * d2 * d;
    float env = 1.0f / d - 28.0f * d5 + 48.0f * d5 * d - 21.0f * d5 * d2;
    #pragma unroll
    for (int i = 0; i < R; ++i) rbf[e * R + i] = env * sinf(freq[i] * d);
}

// ---------------------------------------------------------------------------
// CSR build
// ---------------------------------------------------------------------------
__global__ void k_count(const int* __restrict__ idx, int n, int* __restrict__ cnt) {
    int i = blockIdx.x * 256 + threadIdx.x;
    if (i < n) atomicAdd(&cnt[idx[i]], 1);
}

__global__ __launch_bounds__(256) void k_red(const int* __restrict__ cnt, int n,
                                             int* __restrict__ bsum) {
    __shared__ int ws[4];
    const int tid = threadIdx.x;
    const int base = blockIdx.x * 2048 + tid * 8;
    int s = 0;
    #pragma unroll
    for (int k = 0; k < 8; ++k) { int i = base + k; s += (i < n) ? cnt[i] : 0; }
    #pragma unroll
    for (int off = 32; off; off >>= 1) s += __shfl_down(s, off);
    if ((tid & 63) == 0) ws[tid >> 6] = s;
    __syncthreads();
    if (tid == 0) bsum[blockIdx.x] = ws[0] + ws[1] + ws[2] + ws[3];
}

__global__ void k_scanb(int* __restrict__ b, int nb) {   // nb <= 64
    __shared__ int s[64];
    const int tid = threadIdx.x;
    if (tid < nb) s[tid] = b[tid];
    __syncthreads();
    if (tid == 0) {
        int run = 0;
        for (int i = 0; i < nb; ++i) { int c = s[i]; s[i] = run; run += c; }
    }
    __syncthreads();
    if (tid < nb) b[tid] = s[tid];
}

__global__ __launch_bounds__(256) void k_fill_rs(const int* __restrict__ cnt, int n,
                                                 const int* __restrict__ boff,
                                                 int* __restrict__ rs, int* __restrict__ cur) {
    __shared__ int ts[256];
    const int tid = threadIdx.x;
    const int base = blockIdx.x * 2048 + tid * 8;
    int v[8]; int s = 0;
    #pragma unroll
    for (int k = 0; k < 8; ++k) { int i = base + k; v[k] = (i < n) ? cnt[i] : 0; s += v[k]; }
    ts[tid] = s;
    __syncthreads();
    for (int off = 1; off < 256; off <<= 1) {
        int t = (tid >= off) ? ts[tid - off] : 0;
        __syncthreads();
        ts[tid] += t;
        __syncthreads();
    }
    int ex = boff[blockIdx.x] + ((tid == 0) ? 0 : ts[tid - 1]);
    #pragma unroll
    for (int k = 0; k < 8; ++k) {
        int i = base + k;
        if (i < n) {
            rs[i] = ex; cur[i] = ex; ex += v[k];
            if (i == n - 1) rs[n] = ex;
        }
    }
}

__global__ void k_fill(const int* __restrict__ idx, int n, int* __restrict__ cur,
                       int* __restrict__ perm) {
    int i = blockIdx.x * 256 + threadIdx.x;
    if (i < n) perm[atomicAdd(&cur[idx[i]], 1)] = i;
}

__global__ void k_fill_trip(const int* __restrict__ idx_ji, const int* __restrict__ idx_kj,
                            int n, int* __restrict__ cur,
                            int* __restrict__ kjs, int* __restrict__ rank) {
    int i = blockIdx.x * 256 + threadIdx.x;
    if (i < n) {
        int pos = atomicAdd(&cur[idx_ji[i]], 1);
        kjs[pos] = idx_kj[i];
        rank[i]  = pos;
    }
}

// ---------------------------------------------------------------------------
// Both blocks' sbf projections in ONE pass over sbf
// ---------------------------------------------------------------------------
__global__ __launch_bounds__(256) void k_sbfproj2(
    const float* __restrict__ sbf, const float* __restrict__ W1a,
    const float* __restrict__ W1b, const int* __restrict__ rank,
    float* __restrict__ ta, float* __restrict__ tb)
{
    __shared__ float s_sbf[32 * SR];
    __shared__ float s_Wa[SR * BE];
    __shared__ float s_Wb[SR * BE];
    const int tid = threadIdx.x;
    const int t0  = blockIdx.x * 32;
    for (int i = tid; i < SR * BE; i += 256) { s_Wa[i] = W1a[i]; s_Wb[i] = W1b[i]; }
    const float* sb0 = sbf + (size_t)t0 * SR;
    for (int i = tid; i < 32 * SR; i += 256) s_sbf[i] = sb0[i];
    __syncthreads();
    const int tt = tid >> 3, j = tid & 7;
    float sa = 0.0f, sb = 0.0f;
    #pragma unroll
    for (int i = 0; i < SR; ++i) {
        const float v = s_sbf[tt * SR + i];
        sa = fmaf(v, s_Wa[i * BE + j], sa);
        sb = fmaf(v, s_Wb[i * BE + j], sb);
    }
    const size_t p = (size_t)rank[t0 + tt] * BE + j;
    ta[p] = sa;
    tb[p] = sb;
}

// ---------------------------------------------------------------------------
// Fused front (64-row tile): xji, xkj, rb, down from one staged xe buffer.
// E % 64 == 0 -> no row guards.
// ---------------------------------------------------------------------------
__global__ __launch_bounds__(256, 3) void k_front(
    const float* __restrict__ xe, const float* __restrict__ rbf,
    const float* __restrict__ Wji, const float* __restrict__ bji,
    const float* __restrict__ Wkj, const float* __restrict__ bkj,
    const float* __restrict__ W1, const float* __restrict__ W2,
    const float* __restrict__ Wdown,
    float* __restrict__ xji, float* __restrict__ down)
{
    __shared__ float4 B4[64 * 33];
    __shared__ float s_tj[64 * 8];
    const int tid = threadIdx.x;
    const int r0  = blockIdx.x * 64;
    const int cg = tid & 15, rq = tid >> 4;

    {   // stage xe
        const float4* XG = reinterpret_cast<const float4*>(xe);
        for (int i = tid; i < 64 * 32; i += 256) {
            const int row = i >> 5, kk = i & 31;
            B4[row * 33 + kk] = XG[(size_t)(r0 + row) * 32 + kk];
        }
    }
    // tj[64][8] = rbf_tile @ W1
    for (int i = tid; i < 64 * 8; i += 256) {
        const int row = i >> 3, j = i & 7;
        const float* rr_ = rbf + (size_t)(r0 + row) * R;
        float s = 0.0f;
        #pragma unroll
        for (int q = 0; q < R; ++q) s = fmaf(rr_[q], W1[q * BE + j], s);
        s_tj[i] = s;
    }
    __syncthreads();

    float4 acc[4][2], car[4][2];

    // p0: xji = silu(xe@Wji + b) -> global
    bias48(acc, bji, cg);
    mm48<32, 32>(B4, reinterpret_cast<const float4*>(Wji), cg, rq, acc);
    {
        float4* XJ = reinterpret_cast<float4*>(xji);
        #pragma unroll
        for (int rr = 0; rr < 4; ++rr) {
            const int gr = r0 + rq * 4 + rr;
            XJ[(size_t)gr * 32 + cg*2]     = silu4(acc[rr][0]);
            XJ[(size_t)gr * 32 + cg*2 + 1] = silu4(acc[rr][1]);
        }
    }

    // p1: xkj = silu(xe@Wkj + b); car = xkj .* rb
    bias48(acc, bkj, cg);
    mm48<32, 32>(B4, reinterpret_cast<const float4*>(Wkj), cg, rq, acc);
    {
        const float4* W24 = reinterpret_cast<const float4*>(W2);
        #pragma unroll
        for (int rr = 0; rr < 4; ++rr) {
            const int row = rq * 4 + rr;
            float4 s0 = f4z(), s1 = f4z();
            #pragma unroll
            for (int j = 0; j < 8; ++j) {
                const float t = s_tj[row * 8 + j];
                fma4(s0, t, W24[j * 32 + cg*2]);
                fma4(s1, t, W24[j * 32 + cg*2 + 1]);
            }
            car[rr][0] = mul4(silu4(acc[rr][0]), s0);
            car[rr][1] = mul4(silu4(acc[rr][1]), s1);
        }
    }
    wr48(B4, car, cg, rq);   // B now holds xkj .* rb

    // p2: down = silu(B @ Wdown) (K=128, NCOL=64); 2 rows x 8 cols / thread
    {
        const int cg8 = tid & 7, rq32 = tid >> 3;
        const float4* WD = reinterpret_cast<const float4*>(Wdown);
        float4 a2[2][2];
        #pragma unroll
        for (int rr = 0; rr < 2; ++rr) { a2[rr][0] = f4z(); a2[rr][1] = f4z(); }
        #pragma unroll 4
        for (int k4 = 0; k4 < 32; ++k4) {
            const float4 w0a = WD[(k4*4+0)*16 + cg8*2], w0b = WD[(k4*4+0)*16 + cg8*2+1];
            const float4 w1a = WD[(k4*4+1)*16 + cg8*2], w1b = WD[(k4*4+1)*16 + cg8*2+1];
            const float4 w2a = WD[(k4*4+2)*16 + cg8*2], w2b = WD[(k4*4+2)*16 + cg8*2+1];
            const float4 w3a = WD[(k4*4+3)*16 + cg8*2], w3b = WD[(k4*4+3)*16 + cg8*2+1];
            #pragma unroll
            for (int rr = 0; rr < 2; ++rr) {
                const float4 a = B4[(rq32*2+rr)*33 + k4];
                fma4(a2[rr][0], a.x, w0a); fma4(a2[rr][1], a.x, w0b);
                fma4(a2[rr][0], a.y, w1a); fma4(a2[rr][1], a.y, w1b);
                fma4(a2[rr][0], a.z, w2a); fma4(a2[rr][1], a.z, w2b);
                fma4(a2[rr][0], a.w, w3a); fma4(a2[rr][1], a.w, w3b);
            }
        }
        float4* DG = reinterpret_cast<float4*>(down);
        #pragma unroll
        for (int rr = 0; rr < 2; ++rr) {
            const int gr = r0 + rq32 * 2 + rr;
            DG[(size_t)gr * 16 + cg8*2]     = silu4(a2[rr][0]);
            DG[(size_t)gr * 16 + cg8*2 + 1] = silu4(a2[rr][1]);
        }
    }
}

// ---------------------------------------------------------------------------
// Edge aggregation over sorted triplets (one wave per edge)
// ---------------------------------------------------------------------------
__global__ __launch_bounds__(256) void k_agg(
    const int* __restrict__ rs, const int* __restrict__ kjs,
    const float* __restrict__ tmps, const float* __restrict__ down,
    const float* __restrict__ W2, float* __restrict__ agg)
{
    const int w = threadIdx.x >> 6, lane = threadIdx.x & 63;
    const int e = blockIdx.x * 4 + w;
    float w2[BE];
    #pragma unroll
    for (int j = 0; j < BE; ++j) w2[j] = W2[j * INTD + lane];

    const float4* tmps4 = reinterpret_cast<const float4*>(tmps);
    const int lo = rs[e], hi = rs[e + 1];
    float acc = 0.0f;
    int idx = lo;
    for (; idx + 1 < hi; idx += 2) {
        const int kja = kjs[idx], kjb = kjs[idx + 1];
        const float4 a0 = tmps4[2 * idx],     a1 = tmps4[2 * idx + 1];
        const float4 b0 = tmps4[2 * idx + 2], b1 = tmps4[2 * idx + 3];
        const float da = down[(size_t)kja * INTD + lane];
        const float db = down[(size_t)kjb * INTD + lane];
        float sa = a0.x * w2[0] + a0.y * w2[1] + a0.z * w2[2] + a0.w * w2[3]
                 + a1.x * w2[4] + a1.y * w2[5] + a1.z * w2[6] + a1.w * w2[7];
        float sb = b0.x * w2[0] + b0.y * w2[1] + b0.z * w2[2] + b0.w * w2[3]
                 + b1.x * w2[4] + b1.y * w2[5] + b1.z * w2[6] + b1.w * w2[7];
        acc = fmaf(da, sa, acc);
        acc = fmaf(db, sb, acc);
    }
    if (idx < hi) {
        const int kj = kjs[idx];
        const float4 a0 = tmps4[2 * idx], a1 = tmps4[2 * idx + 1];
        const float d = down[(size_t)kj * INTD + lane];
        float sa = a0.x * w2[0] + a0.y * w2[1] + a0.z * w2[2] + a0.w * w2[3]
                 + a1.x * w2[4] + a1.y * w2[5] + a1.z * w2[6] + a1.w * w2[7];
        acc = fmaf(d, sa, acc);
    }
    agg[(size_t)e * INTD + lane] = acc;
}

// ---------------------------------------------------------------------------
// Fused tail (64-row tile, single LDS buffer, carry in registers):
// h0=silu(agg@Wup)+xji; res0; skip(+xe); res1; res2 -> out
// ---------------------------------------------------------------------------
__global__ __launch_bounds__(256, 3) void k_tail(
    const float* __restrict__ agg, const float* __restrict__ xji,
    const float* __restrict__ xe,
    const float* __restrict__ Wup,
    const float* __restrict__ Wr, const float* __restrict__ br,
    const float* __restrict__ Wlin, const float* __restrict__ blin,
    float* __restrict__ out)
{
    __shared__ float4 B4[64 * 33];
    const int tid = threadIdx.x;
    const int r0  = blockIdx.x * 64;
    const int cg = tid & 15, rq = tid >> 4;

    {   // stage agg (cols 0..15 f4)
        const float4* AG = reinterpret_cast<const float4*>(agg);
        for (int i = tid; i < 64 * 16; i += 256) {
            const int row = i >> 4, kk = i & 15;
            B4[row * 33 + kk] = AG[(size_t)(r0 + row) * 16 + kk];
        }
    }
    __syncthreads();

    float4 acc[4][2], car[4][2];

    // p0: car = silu(agg@Wup) + xji
    z48(acc);
    mm48<16, 32>(B4, reinterpret_cast<const float4*>(Wup), cg, rq, acc);
    {
        const float4* XJ = reinterpret_cast<const float4*>(xji);
        #pragma unroll
        for (int rr = 0; rr < 4; ++rr) {
            const int gr = r0 + rq * 4 + rr;
            car[rr][0] = add4(silu4(acc[rr][0]), XJ[(size_t)gr*32 + cg*2]);
            car[rr][1] = add4(silu4(acc[rr][1]), XJ[(size_t)gr*32 + cg*2+1]);
        }
    }
    wr48(B4, car, cg, rq);

    // p1: t = silu(h@W0+b0)
    bias48(acc, br + 0 * H, cg);
    mm48<32, 32>(B4, reinterpret_cast<const float4*>(Wr + 0 * H * H), cg, rq, acc);
    #pragma unroll
    for (int rr = 0; rr < 4; ++rr) { acc[rr][0] = silu4(acc[rr][0]); acc[rr][1] = silu4(acc[rr][1]); }
    wr48(B4, acc, cg, rq);

    // p2: car += silu(t@W1+b1)
    bias48(acc, br + 1 * H, cg);
    mm48<32, 32>(B4, reinterpret_cast<const float4*>(Wr + 1 * H * H), cg, rq, acc);
    #pragma unroll
    for (int rr = 0; rr < 4; ++rr) {
        car[rr][0] = add4(car[rr][0], silu4(acc[rr][0]));
        car[rr][1] = add4(car[rr][1], silu4(acc[rr][1]));
    }
    wr48(B4, car, cg, rq);

    // p3: car = silu(h@Wlin+blin) + xe
    bias48(acc, blin, cg);
    mm48<32, 32>(B4, reinterpret_cast<const float4*>(Wlin), cg, rq, acc);
    {
        const float4* XG = reinterpret_cast<const float4*>(xe);
        #pragma unroll
        for (int rr = 0; rr < 4; ++rr) {
            const int gr = r0 + rq * 4 + rr;
            car[rr][0] = add4(silu4(acc[rr][0]), XG[(size_t)gr*32 + cg*2]);
            car[rr][1] = add4(silu4(acc[rr][1]), XG[(size_t)gr*32 + cg*2+1]);
        }
    }
    wr48(B4, car, cg, rq);

    // p4: t = silu(car@W2+b2)
    bias48(acc, br + 2 * H, cg);
    mm48<32, 32>(B4, reinterpret_cast<const float4*>(Wr + 2 * H * H), cg, rq, acc);
    #pragma unroll
    for (int rr = 0; rr < 4; ++rr) { acc[rr][0] = silu4(acc[rr][0]); acc[rr][1] = silu4(acc[rr][1]); }
    wr48(B4, acc, cg, rq);

    // p5: car += silu(t@W3+b3)
    bias48(acc, br + 3 * H, cg);
    mm48<32, 32>(B4, reinterpret_cast<const float4*>(Wr + 3 * H * H), cg, rq, acc);
    #pragma unroll
    for (int rr = 0; rr < 4; ++rr) {
        car[rr][0] = add4(car[rr][0], silu4(acc[rr][0]));
        car[rr][1] = add4(car[rr][1], silu4(acc[rr][1]));
    }
    wr48(B4, car, cg, rq);

    // p6: t = silu(car@W4+b4)
    bias48(acc, br + 4 * H, cg);
    mm48<32, 32>(B4, reinterpret_cast<const float4*>(Wr + 4 * H * H), cg, rq, acc);
    #pragma unroll
    for (int rr = 0; rr < 4; ++rr) { acc[rr][0] = silu4(acc[rr][0]); acc[rr][1] = silu4(acc[rr][1]); }
    wr48(B4, acc, cg, rq);

    // p7: out = car + silu(t@W5+b5)
    bias48(acc, br + 5 * H, cg);
    mm48<32, 32>(B4, reinterpret_cast<const float4*>(Wr + 5 * H * H), cg, rq, acc);
    {
        float4* OG = reinterpret_cast<float4*>(out);
        #pragma unroll
        for (int rr = 0; rr < 4; ++rr) {
            const int gr = r0 + rq * 4 + rr;
            OG[(size_t)gr * 32 + cg*2]     = add4(car[rr][0], silu4(acc[rr][0]));
            OG[(size_t)gr * 32 + cg*2 + 1] = add4(car[rr][1], silu4(acc[rr][1]));
        }
    }
}

// ---------------------------------------------------------------------------
// Node aggregation (CSR over edge_i)
// ---------------------------------------------------------------------------
__global__ __launch_bounds__(256) void k_nodes(
    const int* __restrict__ rs, const int* __restrict__ perm,
    const float* __restrict__ rbf, const float* __restrict__ Wrbf,
    const float* __restrict__ xe, float* __restrict__ nodes)
{
    const int tid = threadIdx.x;
    const int n = blockIdx.x * 2 + (tid >> 7);
    const int c = tid & (H - 1);
    float wr[R];
    #pragma unroll
    for (int i = 0; i < R; ++i) wr[i] = Wrbf[i * H + c];
    float acc = 0.0f;
    const int lo = rs[n], hi = rs[n + 1];
    for (int idx = lo; idx < hi; ++idx) {
        const int e = perm[idx];
        const float* rb = rbf + (size_t)e * R;
        float g = 0.0f;
        #pragma unroll
        for (int i = 0; i < R; ++i) g = fmaf(rb[i], wr[i], g);
        acc = fmaf(g, xe[(size_t)e * H + c], acc);
    }
    nodes[(size_t)n * H + c] = acc;
}

// ---------------------------------------------------------------------------
// Fused output chain
// ---------------------------------------------------------------------------
__global__ __launch_bounds__(256) void k_outchain(
    const float* __restrict__ nodes, const float* __restrict__ Wup,
    const float* __restrict__ bup, const float* __restrict__ Wlin,
    const float* __restrict__ blin, const float* __restrict__ Wout,
    float* __restrict__ P)
{
    __shared__ float nb[16 * 132];
    __shared__ float hb[16 * 260];
    __shared__ float tbuf[16 * 260];
    __shared__ float red[64 * 16];
    const int tid = threadIdx.x;
    const int n0  = blockIdx.x * 16;
    float4* nb4 = reinterpret_cast<float4*>(nb);
    float4* hb4 = reinterpret_cast<float4*>(hb);
    float4* tb4 = reinterpret_cast<float4*>(tbuf);
    const float4* NG = reinterpret_cast<const float4*>(nodes);

    for (int i = tid; i < 16 * 32; i += 256) {
        int row = i >> 5, kk = i & 31;
        nb4[row * 33 + kk] = NG[(size_t)(n0 + row) * 32 + kk];
    }
    __syncthreads();

    const int cg = tid & 63, rq = tid >> 6, rbase = rq * 4;
    float acc[4][4];
    auto acc_bias = [&](const float* bias) {
        const float4 bv = reinterpret_cast<const float4*>(bias)[cg];
        #pragma unroll
        for (int r = 0; r < 4; ++r) { acc[r][0]=bv.x; acc[r][1]=bv.y; acc[r][2]=bv.z; acc[r][3]=bv.w; }
    };
    auto mm = [&](const float4* A4, const float4* W4, int K4, int AS4) {
        for (int k4 = 0; k4 < K4; ++k4) {
            const float4 wv0 = W4[(k4*4+0)*64 + cg];
            const float4 wv1 = W4[(k4*4+1)*64 + cg];
            const float4 wv2 = W4[(k4*4+2)*64 + cg];
            const float4 wv3 = W4[(k4*4+3)*64 + cg];
            #pragma unroll
            for (int r = 0; r < 4; ++r) {
                const float4 a = A4[(rbase + r) * AS4 + k4];
                acc[r][0]=fmaf(a.x,wv0.x,acc[r][0]); acc[r][1]=fmaf(a.x,wv0.y,acc[r][1]);
                acc[r][2]=fmaf(a.x,wv0.z,acc[r][2]); acc[r][3]=fmaf(a.x,wv0.w,acc[r][3]);
                acc[r][0]=fmaf(a.y,wv1.x,acc[r][0]); acc[r][1]=fmaf(a.y,wv1.y,acc[r][1]);
                acc[r][2]=fmaf(a.y,wv1.z,acc[r][2]); acc[r][3]=fmaf(a.y,wv1.w,acc[r][3]);
                acc[r][0]=fmaf(a.z,wv2.x,acc[r][0]); acc[r][1]=fmaf(a.z,wv2.y,acc[r][1]);
                acc[r][2]=fmaf(a.z,wv2.z,acc[r][2]); acc[r][3]=fmaf(a.z,wv2.w,acc[r][3]);
                acc[r][0]=fmaf(a.w,wv3.x,acc[r][0]); acc[r][1]=fmaf(a.w,wv3.y,acc[r][1]);
                acc[r][2]=fmaf(a.w,wv3.z,acc[r][2]); acc[r][3]=fmaf(a.w,wv3.w,acc[r][3]);
            }
        }
    };

    acc_bias(bup);
    mm(nb4, reinterpret_cast<const float4*>(Wup), 32, 33);
    #pragma unroll
    for (int r = 0; r < 4; ++r) hb4[(rbase + r) * 65 + cg] = make_float4(acc[r][0],acc[r][1],acc[r][2],acc[r][3]);
    __syncthreads();

    acc_bias(blin + 0 * OE);
    mm(hb4, reinterpret_cast<const float4*>(Wlin + 0 * OE * OE), 64, 65);
    #pragma unroll
    for (int r = 0; r < 4; ++r) tb4[(rbase + r) * 65 + cg] = silu4(make_float4(acc[r][0],acc[r][1],acc[r][2],acc[r][3]));
    __syncthreads();

    acc_bias(blin + 1 * OE);
    mm(tb4, reinterpret_cast<const float4*>(Wlin + 1 * OE * OE), 64, 65);
    #pragma unroll
    for (int r = 0; r < 4; ++r) hb4[(rbase + r) * 65 + cg] = silu4(make_float4(acc[r][0],acc[r][1],acc[r][2],acc[r][3]));
    __syncthreads();

    acc_bias(blin + 2 * OE);
    mm(hb4, reinterpret_cast<const float4*>(Wlin + 2 * OE * OE), 64, 65);
    #pragma unroll
    for (int r = 0; r < 4; ++r) tb4[(rbase + r) * 65 + cg] = silu4(make_float4(acc[r][0],acc[r][1],acc[r][2],acc[r][3]));
    __syncthreads();

    {
        const float4 wo = reinterpret_cast<const float4*>(Wout)[cg];
        #pragma unroll
        for (int r = 0; r < 4; ++r) {
            const int row = rbase + r;
            const float4 hv = tb4[row * 65 + cg];
            red[cg * 16 + row] = hv.x * wo.x + hv.y * wo.y + hv.z * wo.z + hv.w * wo.w;
        }
    }
    __syncthreads();
    if (tid < 16) {
        float s = 0.0f;
        for (int c = 0; c < 64; ++c) s += red[c * 16 + tid];
        P[n0 + tid] += s;
    }
}

// ---------------------------------------------------------------------------
extern "C" void kernel_launch(void* const* d_in, const int* in_sizes, int n_in,
                              void* d_out, int out_size, void* d_ws, size_t ws_size,
                              hipStream_t stream)
{
    (void)in_sizes; (void)n_in; (void)out_size; (void)ws_size;

    const float* x       = (const float*)d_in[0];
    const float* dist    = (const float*)d_in[1];
    const float* freq    = (const float*)d_in[2];
    const float* sbf     = (const float*)d_in[3];
    const int*   idx_kj  = (const int*)d_in[4];
    const int*   idx_ji  = (const int*)d_in[5];
    const int*   edge_i  = (const int*)d_in[6];
    const float* Wi_rbf1 = (const float*)d_in[8];
    const float* Wi_rbf2 = (const float*)d_in[9];
    const float* Wi_sbf1 = (const float*)d_in[10];
    const float* Wi_sbf2 = (const float*)d_in[11];
    const float* Wi_kj   = (const float*)d_in[12];
    const float* bi_kj   = (const float*)d_in[13];
    const float* Wi_ji   = (const float*)d_in[14];
    const float* bi_ji   = (const float*)d_in[15];
    const float* Wi_down = (const float*)d_in[16];
    const float* Wi_up   = (const float*)d_in[17];
    const float* Wi_res  = (const float*)d_in[18];
    const float* bi_res  = (const float*)d_in[19];
    const float* Wi_lin  = (const float*)d_in[20];
    const float* bi_lin  = (const float*)d_in[21];
    const float* Wo_rbf  = (const float*)d_in[22];
    const float* Wo_up   = (const float*)d_in[23];
    const float* bo_up   = (const float*)d_in[24];
    const float* Wo_lin  = (const float*)d_in[25];
    const float* bo_lin  = (const float*)d_in[26];
    const float* Wo_out  = (const float*)d_in[27];
    float* P = (float*)d_out;

    // ---- workspace carve-up ----
    float* w      = (float*)d_ws;
    float* rbf    = w;  w += (size_t)E * R;
    float* xeA    = w;  w += (size_t)E * H;
    float* xeB    = w;  w += (size_t)E * H;
    float* xji    = w;  w += (size_t)E * H;
    float* down   = w;  w += (size_t)E * INTD;
    float* agg    = w;  w += (size_t)E * INTD;
    float* tmp0   = w;  w += (size_t)T * BE;
    float* tmp1   = w;  w += (size_t)T * BE;
    float* nodes  = w;  w += (size_t)NN * H;
    int* ip       = (int*)w;
    int* trip_rs  = ip;  ip += E + 1;
    int* trip_cur = ip;  ip += E;
    int* rank_t   = ip;  ip += T;
    int* kjs      = ip;  ip += T;
    int* edge_rs  = ip;  ip += NN + 1;
    int* edge_cur = ip;  ip += NN;
    int* perm_e   = ip;  ip += E;
    int* bsumT    = ip;  ip += 64;
    int* bsumE    = ip;  ip += 64;

    // ---- CSR build ----
    hipMemsetAsync(trip_cur, 0, (size_t)E * sizeof(int), stream);
    hipMemsetAsync(edge_cur, 0, (size_t)NN * sizeof(int), stream);
    k_count<<<(T + 255) / 256, 256, 0, stream>>>(idx_ji, T, trip_cur);
    k_count<<<(E + 255) / 256, 256, 0, stream>>>(edge_i, E, edge_cur);
    const int nbT = (E + 2047) / 2048, nbE = (NN + 2047) / 2048;
    k_red<<<nbT, 256, 0, stream>>>(trip_cur, E, bsumT);
    k_scanb<<<1, 64, 0, stream>>>(bsumT, nbT);
    k_fill_rs<<<nbT, 256, 0, stream>>>(trip_cur, E, bsumT, trip_rs, trip_cur);
    k_red<<<nbE, 256, 0, stream>>>(edge_cur, NN, bsumE);
    k_scanb<<<1, 64, 0, stream>>>(bsumE, nbE);
    k_fill_rs<<<nbE, 256, 0, stream>>>(edge_cur, NN, bsumE, edge_rs, edge_cur);
    k_fill_trip<<<(T + 255) / 256, 256, 0, stream>>>(idx_ji, idx_kj, T, trip_cur, kjs, rank_t);
    k_fill<<<(E + 255) / 256, 256, 0, stream>>>(edge_i, E, edge_cur, perm_e);

    hipMemsetAsync(d_out, 0, (size_t)NN * sizeof(float), stream);
    k_rbf<<<(E + 255) / 256, 256, 0, stream>>>(dist, freq, rbf);
    k_sbfproj2<<<T / 32, 256, 0, stream>>>(sbf, Wi_sbf1, Wi_sbf1 + (size_t)SR * BE,
                                           rank_t, tmp0, tmp1);

    auto out_block = [&](int b, const float* xe) {
        k_nodes<<<NN / 2, 256, 0, stream>>>(edge_rs, perm_e, rbf,
                                            Wo_rbf + (size_t)b * R * H, xe, nodes);
        k_outchain<<<NN / 16, 256, 0, stream>>>(nodes,
                                                Wo_up + (size_t)b * H * OE,
                                                bo_up + (size_t)b * OE,
                                                Wo_lin + (size_t)b * 3 * OE * OE,
                                                bo_lin + (size_t)b * 3 * OE,
                                                Wo_out + (size_t)b * OE, P);
    };

    const int gE64 = E / 64;
    auto interact = [&](int b, const float* xe, const float* tmp, float* out) {
        k_front<<<gE64, 256, 0, stream>>>(xe, rbf,
                                          Wi_ji + (size_t)b * H * H, bi_ji + (size_t)b * H,
                                          Wi_kj + (size_t)b * H * H, bi_kj + (size_t)b * H,
                                          Wi_rbf1 + (size_t)b * R * BE,
                                          Wi_rbf2 + (size_t)b * BE * H,
                                          Wi_down + (size_t)b * H * INTD,
                                          xji, down);
        k_agg<<<E / 4, 256, 0, stream>>>(trip_rs, kjs, tmp, down,
                                         Wi_sbf2 + (size_t)b * BE * INTD, agg);
        k_tail<<<gE64, 256, 0, stream>>>(agg, xji, xe,
                                         Wi_up + (size_t)b * INTD * H,
                                         Wi_res + (size_t)b * 3 * 2 * H * H,
                                         bi_res + (size_t)b * 3 * 2 * H,
                                         Wi_lin + (size_t)b * H * H,
                                         bi_lin + (size_t)b * H, out);
    };

    out_block(0, x);
    interact(0, x, tmp0, xeB);
    out_block(1, xeB);
    interact(1, xeB, tmp1, xeA);
    out_block(2, xeA);
}

// Round 7
// 1734.863 us; speedup vs baseline: 1.4131x; 1.4131x over previous
//
#include <hip/hip_runtime.h>
#include <hip/hip_bf16.h>

// DimeNet++ forward: k_tail on MFMA (split-bf16, 3-mfma per product); rest f32.
namespace {
constexpr int E     = 120000;
constexpr int T     = 800000;
constexpr int NN    = 12000;
constexpr int H     = 128;
constexpr int INTD  = 64;
constexpr int BE    = 8;
constexpr int R     = 6;
constexpr int SR    = 42;
constexpr int OE    = 256;
constexpr float CUTOFF = 5.0f;
constexpr int PKB   = 122880;  // packed weights per interaction block (8192 + 7*16384)
}

typedef __attribute__((ext_vector_type(8))) short bf16x8;
typedef __attribute__((ext_vector_type(4))) float f32x4;

__device__ __forceinline__ float silu_f(float x) { return x / (1.0f + __expf(-x)); }
__device__ __forceinline__ float4 silu4(float4 v) {
    return make_float4(silu_f(v.x), silu_f(v.y), silu_f(v.z), silu_f(v.w));
}
__device__ __forceinline__ float4 add4(float4 a, float4 b) {
    return make_float4(a.x + b.x, a.y + b.y, a.z + b.z, a.w + b.w);
}
__device__ __forceinline__ float4 mul4(float4 a, float4 b) {
    return make_float4(a.x * b.x, a.y * b.y, a.z * b.z, a.w * b.w);
}
__device__ __forceinline__ void fma4(float4& a, float s, const float4 w) {
    a.x = fmaf(s, w.x, a.x); a.y = fmaf(s, w.y, a.y);
    a.z = fmaf(s, w.z, a.z); a.w = fmaf(s, w.w, a.w);
}
__device__ __forceinline__ float4 f4z() { return make_float4(0.f, 0.f, 0.f, 0.f); }

__device__ __forceinline__ unsigned short bf16_rn(float x) {
    union { float f; unsigned u; } v; v.f = x;
    unsigned r = v.u + 0x7FFFu + ((v.u >> 16) & 1u);
    return (unsigned short)(r >> 16);
}
__device__ __forceinline__ float bf16_f(unsigned short h) {
    union { float f; unsigned u; } v; v.u = ((unsigned)h) << 16;
    return v.f;
}

// ---------------------------------------------------------------------------
// f32 GEMM helpers (k_front / k_outchain, unchanged from round 6)
// ---------------------------------------------------------------------------
template<int K4, int WS4>
__device__ __forceinline__ void mm48(const float4* __restrict__ B4,
                                     const float4* __restrict__ W4,
                                     int cg, int rq, float4 acc[4][2])
{
    #pragma unroll 4
    for (int k4 = 0; k4 < K4; ++k4) {
        const float4 w0a = W4[(k4*4+0)*WS4 + cg*2], w0b = W4[(k4*4+0)*WS4 + cg*2+1];
        const float4 w1a = W4[(k4*4+1)*WS4 + cg*2], w1b = W4[(k4*4+1)*WS4 + cg*2+1];
        const float4 w2a = W4[(k4*4+2)*WS4 + cg*2], w2b = W4[(k4*4+2)*WS4 + cg*2+1];
        const float4 w3a = W4[(k4*4+3)*WS4 + cg*2], w3b = W4[(k4*4+3)*WS4 + cg*2+1];
        #pragma unroll
        for (int rr = 0; rr < 4; ++rr) {
            const float4 a = B4[(rq*4+rr)*33 + k4];
            fma4(acc[rr][0], a.x, w0a); fma4(acc[rr][1], a.x, w0b);
            fma4(acc[rr][0], a.y, w1a); fma4(acc[rr][1], a.y, w1b);
            fma4(acc[rr][0], a.z, w2a); fma4(acc[rr][1], a.z, w2b);
            fma4(acc[rr][0], a.w, w3a); fma4(acc[rr][1], a.w, w3b);
        }
    }
}

__device__ __forceinline__ void bias48(float4 acc[4][2], const float* bias, int cg) {
    const float4 b0 = reinterpret_cast<const float4*>(bias)[cg*2];
    const float4 b1 = reinterpret_cast<const float4*>(bias)[cg*2+1];
    #pragma unroll
    for (int rr = 0; rr < 4; ++rr) { acc[rr][0] = b0; acc[rr][1] = b1; }
}
__device__ __forceinline__ void wr48(float4* B4, const float4 v[4][2], int cg, int rq) {
    __syncthreads();
    #pragma unroll
    for (int rr = 0; rr < 4; ++rr) {
        B4[(rq*4+rr)*33 + cg*2]     = v[rr][0];
        B4[(rq*4+rr)*33 + cg*2 + 1] = v[rr][1];
    }
    __syncthreads();
}

// ---------------------------------------------------------------------------
// rbf[E,6]
// ---------------------------------------------------------------------------
__global__ void k_rbf(const float* __restrict__ dist, const float* __restrict__ freq,
                      float* __restrict__ rbf) {
    int e = blockIdx.x * blockDim.x + threadIdx.x;
    if (e >= E) return;
    float d  = dist[e] * (1.0f / CUTOFF);
    float d2 = d * d;
    float d5 = d2 * d2 * d;
    float env = 1.0f / d - 28.0f * d5 + 48.0f * d5 * d - 21.0f * d5 * d2;
    #pragma unroll
    for (int i = 0; i < R; ++i) rbf[e * R + i] = env * sinf(freq[i] * d);
}

// ---------------------------------------------------------------------------
// CSR build
// ---------------------------------------------------------------------------
__global__ void k_count(const int* __restrict__ idx, int n, int* __restrict__ cnt) {
    int i = blockIdx.x * 256 + threadIdx.x;
    if (i < n) atomicAdd(&cnt[idx[i]], 1);
}

__global__ __launch_bounds__(256) void k_red(const int* __restrict__ cnt, int n,
                                             int* __restrict__ bsum) {
    __shared__ int ws[4];
    const int tid = threadIdx.x;
    const int base = blockIdx.x * 2048 + tid * 8;
    int s = 0;
    #pragma unroll
    for (int k = 0; k < 8; ++k) { int i = base + k; s += (i < n) ? cnt[i] : 0; }
    #pragma unroll
    for (int off = 32; off; off >>= 1) s += __shfl_down(s, off);
    if ((tid & 63) == 0) ws[tid >> 6] = s;
    __syncthreads();
    if (tid == 0) bsum[blockIdx.x] = ws[0] + ws[1] + ws[2] + ws[3];
}

__global__ void k_scanb(int* __restrict__ b, int nb) {   // nb <= 64
    __shared__ int s[64];
    const int tid = threadIdx.x;
    if (tid < nb) s[tid] = b[tid];
    __syncthreads();
    if (tid == 0) {
        int run = 0;
        for (int i = 0; i < nb; ++i) { int c = s[i]; s[i] = run; run += c; }
    }
    __syncthreads();
    if (tid < nb) b[tid] = s[tid];
}

__global__ __launch_bounds__(256) void k_fill_rs(const int* __restrict__ cnt, int n,
                                                 const int* __restrict__ boff,
                                                 int* __restrict__ rs, int* __restrict__ cur) {
    __shared__ int ts[256];
    const int tid = threadIdx.x;
    const int base = blockIdx.x * 2048 + tid * 8;
    int v[8]; int s = 0;
    #pragma unroll
    for (int k = 0; k < 8; ++k) { int i = base + k; v[k] = (i < n) ? cnt[i] : 0; s += v[k]; }
    ts[tid] = s;
    __syncthreads();
    for (int off = 1; off < 256; off <<= 1) {
        int t = (tid >= off) ? ts[tid - off] : 0;
        __syncthreads();
        ts[tid] += t;
        __syncthreads();
    }
    int ex = boff[blockIdx.x] + ((tid == 0) ? 0 : ts[tid - 1]);
    #pragma unroll
    for (int k = 0; k < 8; ++k) {
        int i = base + k;
        if (i < n) {
            rs[i] = ex; cur[i] = ex; ex += v[k];
            if (i == n - 1) rs[n] = ex;
        }
    }
}

__global__ void k_fill(const int* __restrict__ idx, int n, int* __restrict__ cur,
                       int* __restrict__ perm) {
    int i = blockIdx.x * 256 + threadIdx.x;
    if (i < n) perm[atomicAdd(&cur[idx[i]], 1)] = i;
}

__global__ void k_fill_trip(const int* __restrict__ idx_ji, const int* __restrict__ idx_kj,
                            int n, int* __restrict__ cur,
                            int* __restrict__ kjs, int* __restrict__ rank) {
    int i = blockIdx.x * 256 + threadIdx.x;
    if (i < n) {
        int pos = atomicAdd(&cur[idx_ji[i]], 1);
        kjs[pos] = idx_kj[i];
        rank[i]  = pos;
    }
}

// ---------------------------------------------------------------------------
// Pack k_tail weights into MFMA B-fragment order, split bf16 (hi/lo).
// Per interaction block b: [Wup(64x128) | W0 W1 Wlin W2 W3 W4 W5 (128x128 each)]
// Element (kt,nt,lane,j) <- W[kt*32 + (lane>>4)*8 + j][nt*16 + (lane&15)]
// ---------------------------------------------------------------------------
__global__ __launch_bounds__(256) void k_pack(
    const float* __restrict__ Wi_up, const float* __restrict__ Wi_res,
    const float* __restrict__ Wi_lin,
    short* __restrict__ wh, short* __restrict__ wl)
{
    const int g = blockIdx.x * 256 + threadIdx.x;
    if (g >= 2 * PKB) return;
    const int b = g / PKB;
    const int off = g % PKB;
    const float* W;
    int rel;
    if (off < 8192) { W = Wi_up + (size_t)b * 64 * 128; rel = off; }
    else {
        const int i = (off - 8192) / 16384;
        rel = (off - 8192) % 16384;
        if (i == 2) W = Wi_lin + (size_t)b * 128 * 128;
        else {
            const int idx = (i < 2) ? i : i - 1;
            W = Wi_res + (size_t)((b * 3 + idx / 2) * 2 + (idx & 1)) * 128 * 128;
        }
    }
    const int j = rel & 7, lane = (rel >> 3) & 63, q = rel >> 9;
    const int nt = q & 7, kt = q >> 3;
    const int k = kt * 32 + (lane >> 4) * 8 + j;
    const int n = nt * 16 + (lane & 15);
    const float x = W[(size_t)k * 128 + n];
    const unsigned short h = bf16_rn(x);
    wh[g] = (short)h;
    wl[g] = (short)bf16_rn(x - bf16_f(h));
}

// ---------------------------------------------------------------------------
// Both blocks' sbf projections in ONE pass over sbf
// ---------------------------------------------------------------------------
__global__ __launch_bounds__(256) void k_sbfproj2(
    const float* __restrict__ sbf, const float* __restrict__ W1a,
    const float* __restrict__ W1b, const int* __restrict__ rank,
    float* __restrict__ ta, float* __restrict__ tb)
{
    __shared__ float s_sbf[32 * SR];
    __shared__ float s_Wa[SR * BE];
    __shared__ float s_Wb[SR * BE];
    const int tid = threadIdx.x;
    const int t0  = blockIdx.x * 32;
    for (int i = tid; i < SR * BE; i += 256) { s_Wa[i] = W1a[i]; s_Wb[i] = W1b[i]; }
    const float* sb0 = sbf + (size_t)t0 * SR;
    for (int i = tid; i < 32 * SR; i += 256) s_sbf[i] = sb0[i];
    __syncthreads();
    const int tt = tid >> 3, j = tid & 7;
    float sa = 0.0f, sb = 0.0f;
    #pragma unroll
    for (int i = 0; i < SR; ++i) {
        const float v = s_sbf[tt * SR + i];
        sa = fmaf(v, s_Wa[i * BE + j], sa);
        sb = fmaf(v, s_Wb[i * BE + j], sb);
    }
    const size_t p = (size_t)rank[t0 + tt] * BE + j;
    ta[p] = sa;
    tb[p] = sb;
}

// ---------------------------------------------------------------------------
// Fused front (64-row tile), f32 (unchanged from round 6)
// ---------------------------------------------------------------------------
__global__ __launch_bounds__(256, 3) void k_front(
    const float* __restrict__ xe, const float* __restrict__ rbf,
    const float* __restrict__ Wji, const float* __restrict__ bji,
    const float* __restrict__ Wkj, const float* __restrict__ bkj,
    const float* __restrict__ W1, const float* __restrict__ W2,
    const float* __restrict__ Wdown,
    float* __restrict__ xji, float* __restrict__ down)
{
    __shared__ float4 B4[64 * 33];
    __shared__ float s_tj[64 * 8];
    const int tid = threadIdx.x;
    const int r0  = blockIdx.x * 64;
    const int cg = tid & 15, rq = tid >> 4;

    {
        const float4* XG = reinterpret_cast<const float4*>(xe);
        for (int i = tid; i < 64 * 32; i += 256) {
            const int row = i >> 5, kk = i & 31;
            B4[row * 33 + kk] = XG[(size_t)(r0 + row) * 32 + kk];
        }
    }
    for (int i = tid; i < 64 * 8; i += 256) {
        const int row = i >> 3, j = i & 7;
        const float* rr_ = rbf + (size_t)(r0 + row) * R;
        float s = 0.0f;
        #pragma unroll
        for (int q = 0; q < R; ++q) s = fmaf(rr_[q], W1[q * BE + j], s);
        s_tj[i] = s;
    }
    __syncthreads();

    float4 acc[4][2], car[4][2];

    bias48(acc, bji, cg);
    mm48<32, 32>(B4, reinterpret_cast<const float4*>(Wji), cg, rq, acc);
    {
        float4* XJ = reinterpret_cast<float4*>(xji);
        #pragma unroll
        for (int rr = 0; rr < 4; ++rr) {
            const int gr = r0 + rq * 4 + rr;
            XJ[(size_t)gr * 32 + cg*2]     = silu4(acc[rr][0]);
            XJ[(size_t)gr * 32 + cg*2 + 1] = silu4(acc[rr][1]);
        }
    }

    bias48(acc, bkj, cg);
    mm48<32, 32>(B4, reinterpret_cast<const float4*>(Wkj), cg, rq, acc);
    {
        const float4* W24 = reinterpret_cast<const float4*>(W2);
        #pragma unroll
        for (int rr = 0; rr < 4; ++rr) {
            const int row = rq * 4 + rr;
            float4 s0 = f4z(), s1 = f4z();
            #pragma unroll
            for (int j = 0; j < 8; ++j) {
                const float t = s_tj[row * 8 + j];
                fma4(s0, t, W24[j * 32 + cg*2]);
                fma4(s1, t, W24[j * 32 + cg*2 + 1]);
            }
            car[rr][0] = mul4(silu4(acc[rr][0]), s0);
            car[rr][1] = mul4(silu4(acc[rr][1]), s1);
        }
    }
    wr48(B4, car, cg, rq);

    {
        const int cg8 = tid & 7, rq32 = tid >> 3;
        const float4* WD = reinterpret_cast<const float4*>(Wdown);
        float4 a2[2][2];
        #pragma unroll
        for (int rr = 0; rr < 2; ++rr) { a2[rr][0] = f4z(); a2[rr][1] = f4z(); }
        #pragma unroll 4
        for (int k4 = 0; k4 < 32; ++k4) {
            const float4 w0a = WD[(k4*4+0)*16 + cg8*2], w0b = WD[(k4*4+0)*16 + cg8*2+1];
            const float4 w1a = WD[(k4*4+1)*16 + cg8*2], w1b = WD[(k4*4+1)*16 + cg8*2+1];
            const float4 w2a = WD[(k4*4+2)*16 + cg8*2], w2b = WD[(k4*4+2)*16 + cg8*2+1];
            const float4 w3a = WD[(k4*4+3)*16 + cg8*2], w3b = WD[(k4*4+3)*16 + cg8*2+1];
            #pragma unroll
            for (int rr = 0; rr < 2; ++rr) {
                const float4 a = B4[(rq32*2+rr)*33 + k4];
                fma4(a2[rr][0], a.x, w0a); fma4(a2[rr][1], a.x, w0b);
                fma4(a2[rr][0], a.y, w1a); fma4(a2[rr][1], a.y, w1b);
                fma4(a2[rr][0], a.z, w2a); fma4(a2[rr][1], a.z, w2b);
                fma4(a2[rr][0], a.w, w3a); fma4(a2[rr][1], a.w, w3b);
            }
        }
        float4* DG = reinterpret_cast<float4*>(down);
        #pragma unroll
        for (int rr = 0; rr < 2; ++rr) {
            const int gr = r0 + rq32 * 2 + rr;
            DG[(size_t)gr * 16 + cg8*2]     = silu4(a2[rr][0]);
            DG[(size_t)gr * 16 + cg8*2 + 1] = silu4(a2[rr][1]);
        }
    }
}

// ---------------------------------------------------------------------------
// Edge aggregation over sorted triplets (one wave per edge)
// ---------------------------------------------------------------------------
__global__ __launch_bounds__(256) void k_agg(
    const int* __restrict__ rs, const int* __restrict__ kjs,
    const float* __restrict__ tmps, const float* __restrict__ down,
    const float* __restrict__ W2, float* __restrict__ agg)
{
    const int w = threadIdx.x >> 6, lane = threadIdx.x & 63;
    const int e = blockIdx.x * 4 + w;
    float w2[BE];
    #pragma unroll
    for (int j = 0; j < BE; ++j) w2[j] = W2[j * INTD + lane];

    const float4* tmps4 = reinterpret_cast<const float4*>(tmps);
    const int lo = rs[e], hi = rs[e + 1];
    float acc = 0.0f;
    int idx = lo;
    for (; idx + 1 < hi; idx += 2) {
        const int kja = kjs[idx], kjb = kjs[idx + 1];
        const float4 a0 = tmps4[2 * idx],     a1 = tmps4[2 * idx + 1];
        const float4 b0 = tmps4[2 * idx + 2], b1 = tmps4[2 * idx + 3];
        const float da = down[(size_t)kja * INTD + lane];
        const float db = down[(size_t)kjb * INTD + lane];
        float sa = a0.x * w2[0] + a0.y * w2[1] + a0.z * w2[2] + a0.w * w2[3]
                 + a1.x * w2[4] + a1.y * w2[5] + a1.z * w2[6] + a1.w * w2[7];
        float sb = b0.x * w2[0] + b0.y * w2[1] + b0.z * w2[2] + b0.w * w2[3]
                 + b1.x * w2[4] + b1.y * w2[5] + b1.z * w2[6] + b1.w * w2[7];
        acc = fmaf(da, sa, acc);
        acc = fmaf(db, sb, acc);
    }
    if (idx < hi) {
        const int kj = kjs[idx];
        const float4 a0 = tmps4[2 * idx], a1 = tmps4[2 * idx + 1];
        const float d = down[(size_t)kj * INTD + lane];
        float sa = a0.x * w2[0] + a0.y * w2[1] + a0.z * w2[2] + a0.w * w2[3]
                 + a1.x * w2[4] + a1.y * w2[5] + a1.z * w2[6] + a1.w * w2[7];
        acc = fmaf(d, sa, acc);
    }
    agg[(size_t)e * INTD + lane] = acc;
}

// ---------------------------------------------------------------------------
// MFMA fused tail (64-row tile, split-bf16, 3 mfma per product).
// Wave w owns cols 32w..32w+31 (ntiles 2w,2w+1); 4 mtiles (rows 0..63).
// A (activations) split hi/lo bf16 in LDS, row stride 136.
// Phases: p0 h=silu(agg@Wup)+xji; p1..p7 residual/skip chain as before.
// ---------------------------------------------------------------------------
__global__ __launch_bounds__(256, 2) void k_tail_mfma(
    const float* __restrict__ agg, const float* __restrict__ xji,
    const float* __restrict__ xe,
    const short* __restrict__ wh, const short* __restrict__ wl,
    const float* __restrict__ br, const float* __restrict__ blin,
    float* __restrict__ out)
{
    __shared__ short Ah[64 * 136];
    __shared__ short Al[64 * 136];
    const int tid = threadIdx.x;
    const int r0  = blockIdx.x * 64;
    const int lane = tid & 63, wv = tid >> 6;
    const int lo4 = lane & 15, hi4 = lane >> 4;

    // stage agg (64 x 64 f32) -> split bf16 LDS
    {
        const float4* AG = reinterpret_cast<const float4*>(agg);
        for (int i = tid; i < 64 * 16; i += 256) {
            const int row = i >> 4, c4 = i & 15;
            const float4 v = AG[(size_t)(r0 + row) * 16 + c4];
            unsigned short h0 = bf16_rn(v.x), h1 = bf16_rn(v.y),
                           h2 = bf16_rn(v.z), h3 = bf16_rn(v.w);
            ushort4 hv = make_ushort4(h0, h1, h2, h3);
            ushort4 lv = make_ushort4(bf16_rn(v.x - bf16_f(h0)),
                                      bf16_rn(v.y - bf16_f(h1)),
                                      bf16_rn(v.z - bf16_f(h2)),
                                      bf16_rn(v.w - bf16_f(h3)));
            *reinterpret_cast<ushort4*>(&Ah[row * 136 + c4 * 4]) = hv;
            *reinterpret_cast<ushort4*>(&Al[row * 136 + c4 * 4]) = lv;
        }
    }
    __syncthreads();

    f32x4 acc[4][2], car[4][2];

    auto gemm = [&](const short* Wh, const short* Wl, int nkt) {
        #pragma unroll
        for (int m = 0; m < 4; ++m)
            #pragma unroll
            for (int n = 0; n < 2; ++n) acc[m][n] = (f32x4)0.0f;
        for (int kt = 0; kt < nkt; ++kt) {
            bf16x8 ahf[4], alf[4], bhf[2], blf[2];
            #pragma unroll
            for (int m = 0; m < 4; ++m) {
                const int off = (m * 16 + lo4) * 136 + kt * 32 + hi4 * 8;
                ahf[m] = *reinterpret_cast<const bf16x8*>(&Ah[off]);
                alf[m] = *reinterpret_cast<const bf16x8*>(&Al[off]);
            }
            #pragma unroll
            for (int n = 0; n < 2; ++n) {
                const size_t boff = ((size_t)((kt * 8 + wv * 2 + n) * 64) + lane) * 8;
                bhf[n] = *reinterpret_cast<const bf16x8*>(&Wh[boff]);
                blf[n] = *reinterpret_cast<const bf16x8*>(&Wl[boff]);
            }
            #pragma unroll
            for (int m = 0; m < 4; ++m)
                #pragma unroll
                for (int n = 0; n < 2; ++n) {
                    acc[m][n] = __builtin_amdgcn_mfma_f32_16x16x32_bf16(ahf[m], bhf[n], acc[m][n], 0, 0, 0);
                    acc[m][n] = __builtin_amdgcn_mfma_f32_16x16x32_bf16(ahf[m], blf[n], acc[m][n], 0, 0, 0);
                    acc[m][n] = __builtin_amdgcn_mfma_f32_16x16x32_bf16(alf[m], bhf[n], acc[m][n], 0, 0, 0);
                }
        }
    };

    auto wrA = [&](f32x4 v[4][2]) {
        __syncthreads();
        #pragma unroll
        for (int m = 0; m < 4; ++m)
            #pragma unroll
            for (int n = 0; n < 2; ++n) {
                const int col = (wv * 2 + n) * 16 + lo4;
                #pragma unroll
                for (int r = 0; r < 4; ++r) {
                    const int row = m * 16 + hi4 * 4 + r;
                    const float x = v[m][n][r];
                    const unsigned short h = bf16_rn(x);
                    Ah[row * 136 + col] = (short)h;
                    Al[row * 136 + col] = (short)bf16_rn(x - bf16_f(h));
                }
            }
        __syncthreads();
    };

    // p0: car = silu(agg@Wup) + xji
    gemm(wh, wl, 2);
    #pragma unroll
    for (int m = 0; m < 4; ++m)
        #pragma unroll
        for (int n = 0; n < 2; ++n) {
            const int col = (wv * 2 + n) * 16 + lo4;
            #pragma unroll
            for (int r = 0; r < 4; ++r) {
                const int row = r0 + m * 16 + hi4 * 4 + r;
                car[m][n][r] = silu_f(acc[m][n][r]) + xji[(size_t)row * 128 + col];
            }
        }
    wrA(car);

    // t-phase: A <- silu(acc + bias)
    auto tphase = [&](const short* Wh, const short* Wl, const float* bias) {
        gemm(Wh, Wl, 4);
        #pragma unroll
        for (int m = 0; m < 4; ++m)
            #pragma unroll
            for (int n = 0; n < 2; ++n) {
                const float bb = bias[(wv * 2 + n) * 16 + lo4];
                #pragma unroll
                for (int r = 0; r < 4; ++r)
                    acc[m][n][r] = silu_f(acc[m][n][r] + bb);
            }
        wrA(acc);
    };
    // c-phase: car += silu(acc + bias); A <- car
    auto cphase = [&](const short* Wh, const short* Wl, const float* bias) {
        gemm(Wh, Wl, 4);
        #pragma unroll
        for (int m = 0; m < 4; ++m)
            #pragma unroll
            for (int n = 0; n < 2; ++n) {
                const float bb = bias[(wv * 2 + n) * 16 + lo4];
                #pragma unroll
                for (int r = 0; r < 4; ++r)
                    car[m][n][r] += silu_f(acc[m][n][r] + bb);
            }
        wrA(car);
    };

    tphase(wh + 8192,              wl + 8192,              br + 0 * 128);   // p1: W0
    cphase(wh + 8192 + 16384,      wl + 8192 + 16384,      br + 1 * 128);   // p2: W1

    // p3: car = silu(acc + blin) + xe
    gemm(wh + 8192 + 2 * 16384, wl + 8192 + 2 * 16384, 4);
    #pragma unroll
    for (int m = 0; m < 4; ++m)
        #pragma unroll
        for (int n = 0; n < 2; ++n) {
            const int col = (wv * 2 + n) * 16 + lo4;
            const float bb = blin[col];
            #pragma unroll
            for (int r = 0; r < 4; ++r) {
                const int row = r0 + m * 16 + hi4 * 4 + r;
                car[m][n][r] = silu_f(acc[m][n][r] + bb) + xe[(size_t)row * 128 + col];
            }
        }
    wrA(car);

    tphase(wh + 8192 + 3 * 16384, wl + 8192 + 3 * 16384, br + 2 * 128);     // p4: W2
    cphase(wh + 8192 + 4 * 16384, wl + 8192 + 4 * 16384, br + 3 * 128);     // p5: W3
    tphase(wh + 8192 + 5 * 16384, wl + 8192 + 5 * 16384, br + 4 * 128);     // p6: W4

    // p7: out = car + silu(acc + b5)
    gemm(wh + 8192 + 6 * 16384, wl + 8192 + 6 * 16384, 4);
    #pragma unroll
    for (int m = 0; m < 4; ++m)
        #pragma unroll
        for (int n = 0; n < 2; ++n) {
            const int col = (wv * 2 + n) * 16 + lo4;
            const float bb = br[5 * 128 + col];
            #pragma unroll
            for (int r = 0; r < 4; ++r) {
                const int row = r0 + m * 16 + hi4 * 4 + r;
                out[(size_t)row * 128 + col] = car[m][n][r] + silu_f(acc[m][n][r] + bb);
            }
        }
}

// ---------------------------------------------------------------------------
// Node aggregation (CSR over edge_i)
// ---------------------------------------------------------------------------
__global__ __launch_bounds__(256) void k_nodes(
    const int* __restrict__ rs, const int* __restrict__ perm,
    const float* __restrict__ rbf, const float* __restrict__ Wrbf,
    const float* __restrict__ xe, float* __restrict__ nodes)
{
    const int tid = threadIdx.x;
    const int n = blockIdx.x * 2 + (tid >> 7);
    const int c = tid & (H - 1);
    float wr[R];
    #pragma unroll
    for (int i = 0; i < R; ++i) wr[i] = Wrbf[i * H + c];
    float acc = 0.0f;
    const int lo = rs[n], hi = rs[n + 1];
    for (int idx = lo; idx < hi; ++idx) {
        const int e = perm[idx];
        const float* rb = rbf + (size_t)e * R;
        float g = 0.0f;
        #pragma unroll
        for (int i = 0; i < R; ++i) g = fmaf(rb[i], wr[i], g);
        acc = fmaf(g, xe[(size_t)e * H + c], acc);
    }
    nodes[(size_t)n * H + c] = acc;
}

// ---------------------------------------------------------------------------
// Fused output chain (f32, unchanged)
// ---------------------------------------------------------------------------
__global__ __launch_bounds__(256) void k_outchain(
    const float* __restrict__ nodes, const float* __restrict__ Wup,
    const float* __restrict__ bup, const float* __restrict__ Wlin,
    const float* __restrict__ blin, const float* __restrict__ Wout,
    float* __restrict__ P)
{
    __shared__ float nb[16 * 132];
    __shared__ float hb[16 * 260];
    __shared__ float tbuf[16 * 260];
    __shared__ float red[64 * 16];
    const int tid = threadIdx.x;
    const int n0  = blockIdx.x * 16;
    float4* nb4 = reinterpret_cast<float4*>(nb);
    float4* hb4 = reinterpret_cast<float4*>(hb);
    float4* tb4 = reinterpret_cast<float4*>(tbuf);
    const float4* NG = reinterpret_cast<const float4*>(nodes);

    for (int i = tid; i < 16 * 32; i += 256) {
        int row = i >> 5, kk = i & 31;
        nb4[row * 33 + kk] = NG[(size_t)(n0 + row) * 32 + kk];
    }
    __syncthreads();

    const int cg = tid & 63, rq = tid >> 6, rbase = rq * 4;
    float acc[4][4];
    auto acc_bias = [&](const float* bias) {
        const float4 bv = reinterpret_cast<const float4*>(bias)[cg];
        #pragma unroll
        for (int r = 0; r < 4; ++r) { acc[r][0]=bv.x; acc[r][1]=bv.y; acc[r][2]=bv.z; acc[r][3]=bv.w; }
    };
    auto mm = [&](const float4* A4, const float4* W4, int K4, int AS4) {
        for (int k4 = 0; k4 < K4; ++k4) {
            const float4 wv0 = W4[(k4*4+0)*64 + cg];
            const float4 wv1 = W4[(k4*4+1)*64 + cg];
            const float4 wv2 = W4[(k4*4+2)*64 + cg];
            const float4 wv3 = W4[(k4*4+3)*64 + cg];
            #pragma unroll
            for (int r = 0; r < 4; ++r) {
                const float4 a = A4[(rbase + r) * AS4 + k4];
                acc[r][0]=fmaf(a.x,wv0.x,acc[r][0]); acc[r][1]=fmaf(a.x,wv0.y,acc[r][1]);
                acc[r][2]=fmaf(a.x,wv0.z,acc[r][2]); acc[r][3]=fmaf(a.x,wv0.w,acc[r][3]);
                acc[r][0]=fmaf(a.y,wv1.x,acc[r][0]); acc[r][1]=fmaf(a.y,wv1.y,acc[r][1]);
                acc[r][2]=fmaf(a.y,wv1.z,acc[r][2]); acc[r][3]=fmaf(a.y,wv1.w,acc[r][3]);
                acc[r][0]=fmaf(a.z,wv2.x,acc[r][0]); acc[r][1]=fmaf(a.z,wv2.y,acc[r][1]);
                acc[r][2]=fmaf(a.z,wv2.z,acc[r][2]); acc[r][3]=fmaf(a.z,wv2.w,acc[r][3]);
                acc[r][0]=fmaf(a.w,wv3.x,acc[r][0]); acc[r][1]=fmaf(a.w,wv3.y,acc[r][1]);
                acc[r][2]=fmaf(a.w,wv3.z,acc[r][2]); acc[r][3]=fmaf(a.w,wv3.w,acc[r][3]);
            }
        }
    };

    acc_bias(bup);
    mm(nb4, reinterpret_cast<const float4*>(Wup), 32, 33);
    #pragma unroll
    for (int r = 0; r < 4; ++r) hb4[(rbase + r) * 65 + cg] = make_float4(acc[r][0],acc[r][1],acc[r][2],acc[r][3]);
    __syncthreads();

    acc_bias(blin + 0 * OE);
    mm(hb4, reinterpret_cast<const float4*>(Wlin + 0 * OE * OE), 64, 65);
    #pragma unroll
    for (int r = 0; r < 4; ++r) tb4[(rbase + r) * 65 + cg] = silu4(make_float4(acc[r][0],acc[r][1],acc[r][2],acc[r][3]));
    __syncthreads();

    acc_bias(blin + 1 * OE);
    mm(tb4, reinterpret_cast<const float4*>(Wlin + 1 * OE * OE), 64, 65);
    #pragma unroll
    for (int r = 0; r < 4; ++r) hb4[(rbase + r) * 65 + cg] = silu4(make_float4(acc[r][0],acc[r][1],acc[r][2],acc[r][3]));
    __syncthreads();

    acc_bias(blin + 2 * OE);
    mm(hb4, reinterpret_cast<const float4*>(Wlin + 2 * OE * OE), 64, 65);
    #pragma unroll
    for (int r = 0; r < 4; ++r) tb4[(rbase + r) * 65 + cg] = silu4(make_float4(acc[r][0],acc[r][1],acc[r][2],acc[r][3]));
    __syncthreads();

    {
        const float4 wo = reinterpret_cast<const float4*>(Wout)[cg];
        #pragma unroll
        for (int r = 0; r < 4; ++r) {
            const int row = rbase + r;
            const float4 hv = tb4[row * 65 + cg];
            red[cg * 16 + row] = hv.x * wo.x + hv.y * wo.y + hv.z * wo.z + hv.w * wo.w;
        }
    }
    __syncthreads();
    if (tid < 16) {
        float s = 0.0f;
        for (int c = 0; c < 64; ++c) s += red[c * 16 + tid];
        P[n0 + tid] += s;
    }
}

// ---------------------------------------------------------------------------
extern "C" void kernel_launch(void* const* d_in, const int* in_sizes, int n_in,
                              void* d_out, int out_size, void* d_ws, size_t ws_size,
                              hipStream_t stream)
{
    (void)in_sizes; (void)n_in; (void)out_size; (void)ws_size;

    const float* x       = (const float*)d_in[0];
    const float* dist    = (const float*)d_in[1];
    const float* freq    = (const float*)d_in[2];
    const float* sbf     = (const float*)d_in[3];
    const int*   idx_kj  = (const int*)d_in[4];
    const int*   idx_ji  = (const int*)d_in[5];
    const int*   edge_i  = (const int*)d_in[6];
    const float* Wi_rbf1 = (const float*)d_in[8];
    const float* Wi_rbf2 = (const float*)d_in[9];
    const float* Wi_sbf1 = (const float*)d_in[10];
    const float* Wi_sbf2 = (const float*)d_in[11];
    const float* Wi_kj   = (const float*)d_in[12];
    const float* bi_kj   = (const float*)d_in[13];
    const float* Wi_ji   = (const float*)d_in[14];
    const float* bi_ji   = (const float*)d_in[15];
    const float* Wi_down = (const float*)d_in[16];
    const float* Wi_up   = (const float*)d_in[17];
    const float* Wi_res  = (const float*)d_in[18];
    const float* bi_res  = (const float*)d_in[19];
    const float* Wi_lin  = (const float*)d_in[20];
    const float* bi_lin  = (const float*)d_in[21];
    const float* Wo_rbf  = (const float*)d_in[22];
    const float* Wo_up   = (const float*)d_in[23];
    const float* bo_up   = (const float*)d_in[24];
    const float* Wo_lin  = (const float*)d_in[25];
    const float* bo_lin  = (const float*)d_in[26];
    const float* Wo_out  = (const float*)d_in[27];
    float* P = (float*)d_out;

    // ---- workspace carve-up ----
    float* w      = (float*)d_ws;
    float* rbf    = w;  w += (size_t)E * R;
    float* xeA    = w;  w += (size_t)E * H;
    float* xeB    = w;  w += (size_t)E * H;
    float* xji    = w;  w += (size_t)E * H;
    float* down   = w;  w += (size_t)E * INTD;
    float* agg    = w;  w += (size_t)E * INTD;
    float* tmp0   = w;  w += (size_t)T * BE;
    float* tmp1   = w;  w += (size_t)T * BE;
    float* nodes  = w;  w += (size_t)NN * H;
    int* ip       = (int*)w;
    int* trip_rs  = ip;  ip += E + 1;
    int* trip_cur = ip;  ip += E;
    int* rank_t   = ip;  ip += T;
    int* kjs      = ip;  ip += T;
    int* edge_rs  = ip;  ip += NN + 1;
    int* edge_cur = ip;  ip += NN;
    int* perm_e   = ip;  ip += E;
    int* bsumT    = ip;  ip += 64;
    int* bsumE    = ip;  ip += 64;
    short* wpk_hi = (short*)ip;
    short* wpk_lo = wpk_hi + 2 * PKB;

    // ---- CSR build ----
    hipMemsetAsync(trip_cur, 0, (size_t)E * sizeof(int), stream);
    hipMemsetAsync(edge_cur, 0, (size_t)NN * sizeof(int), stream);
    k_count<<<(T + 255) / 256, 256, 0, stream>>>(idx_ji, T, trip_cur);
    k_count<<<(E + 255) / 256, 256, 0, stream>>>(edge_i, E, edge_cur);
    const int nbT = (E + 2047) / 2048, nbE = (NN + 2047) / 2048;
    k_red<<<nbT, 256, 0, stream>>>(trip_cur, E, bsumT);
    k_scanb<<<1, 64, 0, stream>>>(bsumT, nbT);
    k_fill_rs<<<nbT, 256, 0, stream>>>(trip_cur, E, bsumT, trip_rs, trip_cur);
    k_red<<<nbE, 256, 0, stream>>>(edge_cur, NN, bsumE);
    k_scanb<<<1, 64, 0, stream>>>(bsumE, nbE);
    k_fill_rs<<<nbE, 256, 0, stream>>>(edge_cur, NN, bsumE, edge_rs, edge_cur);
    k_fill_trip<<<(T + 255) / 256, 256, 0, stream>>>(idx_ji, idx_kj, T, trip_cur, kjs, rank_t);
    k_fill<<<(E + 255) / 256, 256, 0, stream>>>(edge_i, E, edge_cur, perm_e);

    hipMemsetAsync(d_out, 0, (size_t)NN * sizeof(float), stream);
    k_rbf<<<(E + 255) / 256, 256, 0, stream>>>(dist, freq, rbf);
    k_pack<<<(2 * PKB + 255) / 256, 256, 0, stream>>>(Wi_up, Wi_res, Wi_lin, wpk_hi, wpk_lo);
    k_sbfproj2<<<T / 32, 256, 0, stream>>>(sbf, Wi_sbf1, Wi_sbf1 + (size_t)SR * BE,
                                           rank_t, tmp0, tmp1);

    auto out_block = [&](int b, const float* xe) {
        k_nodes<<<NN / 2, 256, 0, stream>>>(edge_rs, perm_e, rbf,
                                            Wo_rbf + (size_t)b * R * H, xe, nodes);
        k_outchain<<<NN / 16, 256, 0, stream>>>(nodes,
                                                Wo_up + (size_t)b * H * OE,
                                                bo_up + (size_t)b * OE,
                                                Wo_lin + (size_t)b * 3 * OE * OE,
                                                bo_lin + (size_t)b * 3 * OE,
                                                Wo_out + (size_t)b * OE, P);
    };

    const int gE64 = E / 64;
    auto interact = [&](int b, const float* xe, const float* tmp, float* out) {
        k_front<<<gE64, 256, 0, stream>>>(xe, rbf,
                                          Wi_ji + (size_t)b * H * H, bi_ji + (size_t)b * H,
                                          Wi_kj + (size_t)b * H * H, bi_kj + (size_t)b * H,
                                          Wi_rbf1 + (size_t)b * R * BE,
                                          Wi_rbf2 + (size_t)b * BE * H,
                                          Wi_down + (size_t)b * H * INTD,
                                          xji, down);
        k_agg<<<E / 4, 256, 0, stream>>>(trip_rs, kjs, tmp, down,
                                         Wi_sbf2 + (size_t)b * BE * INTD, agg);
        k_tail_mfma<<<gE64, 256, 0, stream>>>(agg, xji, xe,
                                              wpk_hi + (size_t)b * PKB,
                                              wpk_lo + (size_t)b * PKB,
                                              bi_res + (size_t)b * 3 * 2 * H,
                                              bi_lin + (size_t)b * H, out);
    };

    out_block(0, x);
    interact(0, x, tmp0, xeB);
    out_block(1, xeB);
    interact(1, xeB, tmp1, xeA);
    out_block(2, xeA);
}

// Round 8
// 1486.131 us; speedup vs baseline: 1.6497x; 1.1674x over previous
//
#include <hip/hip_runtime.h>
#include <hip/hip_bf16.h>

// DimeNet++ forward: k_front + k_tail on MFMA (split-bf16); rest f32.
namespace {
constexpr int E     = 120000;
constexpr int T     = 800000;
constexpr int NN    = 12000;
constexpr int H     = 128;
constexpr int INTD  = 64;
constexpr int BE    = 8;
constexpr int R     = 6;
constexpr int SR    = 42;
constexpr int OE    = 256;
constexpr float CUTOFF = 5.0f;
// packed weights per interaction block:
// [Wji 16384 | Wkj 16384 | Wdown 8192 | Wup 8192 | W0 W1 Wlin W2 W3 W4 W5 7x16384]
constexpr int PKB   = 163840;
constexpr int TAILO = 40960;   // tail base offset within a block
}

typedef __attribute__((ext_vector_type(8))) short bf16x8;
typedef __attribute__((ext_vector_type(4))) float f32x4;

__device__ __forceinline__ float silu_f(float x) { return x / (1.0f + __expf(-x)); }
__device__ __forceinline__ float4 silu4(float4 v) {
    return make_float4(silu_f(v.x), silu_f(v.y), silu_f(v.z), silu_f(v.w));
}

__device__ __forceinline__ unsigned short bf16_rn(float x) {
    union { float f; unsigned u; } v; v.f = x;
    unsigned r = v.u + 0x7FFFu + ((v.u >> 16) & 1u);
    return (unsigned short)(r >> 16);
}
__device__ __forceinline__ float bf16_f(unsigned short h) {
    union { float f; unsigned u; } v; v.u = ((unsigned)h) << 16;
    return v.f;
}

// ---------------------------------------------------------------------------
// rbf[E,6]
// ---------------------------------------------------------------------------
__global__ void k_rbf(const float* __restrict__ dist, const float* __restrict__ freq,
                      float* __restrict__ rbf) {
    int e = blockIdx.x * blockDim.x + threadIdx.x;
    if (e >= E) return;
    float d  = dist[e] * (1.0f / CUTOFF);
    float d2 = d * d;
    float d5 = d2 * d2 * d;
    float env = 1.0f / d - 28.0f * d5 + 48.0f * d5 * d - 21.0f * d5 * d2;
    #pragma unroll
    for (int i = 0; i < R; ++i) rbf[e * R + i] = env * sinf(freq[i] * d);
}

// ---------------------------------------------------------------------------
// CSR build
// ---------------------------------------------------------------------------
__global__ void k_count(const int* __restrict__ idx, int n, int* __restrict__ cnt) {
    int i = blockIdx.x * 256 + threadIdx.x;
    if (i < n) atomicAdd(&cnt[idx[i]], 1);
}

__global__ __launch_bounds__(256) void k_red(const int* __restrict__ cnt, int n,
                                             int* __restrict__ bsum) {
    __shared__ int ws[4];
    const int tid = threadIdx.x;
    const int base = blockIdx.x * 2048 + tid * 8;
    int s = 0;
    #pragma unroll
    for (int k = 0; k < 8; ++k) { int i = base + k; s += (i < n) ? cnt[i] : 0; }
    #pragma unroll
    for (int off = 32; off; off >>= 1) s += __shfl_down(s, off);
    if ((tid & 63) == 0) ws[tid >> 6] = s;
    __syncthreads();
    if (tid == 0) bsum[blockIdx.x] = ws[0] + ws[1] + ws[2] + ws[3];
}

__global__ void k_scanb(int* __restrict__ b, int nb) {   // nb <= 64
    __shared__ int s[64];
    const int tid = threadIdx.x;
    if (tid < nb) s[tid] = b[tid];
    __syncthreads();
    if (tid == 0) {
        int run = 0;
        for (int i = 0; i < nb; ++i) { int c = s[i]; s[i] = run; run += c; }
    }
    __syncthreads();
    if (tid < nb) b[tid] = s[tid];
}

__global__ __launch_bounds__(256) void k_fill_rs(const int* __restrict__ cnt, int n,
                                                 const int* __restrict__ boff,
                                                 int* __restrict__ rs, int* __restrict__ cur) {
    __shared__ int ts[256];
    const int tid = threadIdx.x;
    const int base = blockIdx.x * 2048 + tid * 8;
    int v[8]; int s = 0;
    #pragma unroll
    for (int k = 0; k < 8; ++k) { int i = base + k; v[k] = (i < n) ? cnt[i] : 0; s += v[k]; }
    ts[tid] = s;
    __syncthreads();
    for (int off = 1; off < 256; off <<= 1) {
        int t = (tid >= off) ? ts[tid - off] : 0;
        __syncthreads();
        ts[tid] += t;
        __syncthreads();
    }
    int ex = boff[blockIdx.x] + ((tid == 0) ? 0 : ts[tid - 1]);
    #pragma unroll
    for (int k = 0; k < 8; ++k) {
        int i = base + k;
        if (i < n) {
            rs[i] = ex; cur[i] = ex; ex += v[k];
            if (i == n - 1) rs[n] = ex;
        }
    }
}

__global__ void k_fill(const int* __restrict__ idx, int n, int* __restrict__ cur,
                       int* __restrict__ perm) {
    int i = blockIdx.x * 256 + threadIdx.x;
    if (i < n) perm[atomicAdd(&cur[idx[i]], 1)] = i;
}

__global__ void k_fill_trip(const int* __restrict__ idx_ji, const int* __restrict__ idx_kj,
                            int n, int* __restrict__ cur,
                            int* __restrict__ kjs, int* __restrict__ rank) {
    int i = blockIdx.x * 256 + threadIdx.x;
    if (i < n) {
        int pos = atomicAdd(&cur[idx_ji[i]], 1);
        kjs[pos] = idx_kj[i];
        rank[i]  = pos;
    }
}

// ---------------------------------------------------------------------------
// Pack all interaction weights into MFMA B-fragment order, split bf16.
// Element (kt,nt,lane,j) <- W[kt*32 + (lane>>4)*8 + j][nt*16 + (lane&15)]
// ---------------------------------------------------------------------------
__global__ __launch_bounds__(256) void k_pack(
    const float* __restrict__ Wi_ji, const float* __restrict__ Wi_kj,
    const float* __restrict__ Wi_down,
    const float* __restrict__ Wi_up, const float* __restrict__ Wi_res,
    const float* __restrict__ Wi_lin,
    short* __restrict__ wh, short* __restrict__ wl)
{
    const int g = blockIdx.x * 256 + threadIdx.x;
    if (g >= 2 * PKB) return;
    const int b = g / PKB;
    const int off = g % PKB;
    const float* W;
    int rel, NT;
    if (off < 16384)      { W = Wi_ji   + (size_t)b * 16384; rel = off;          NT = 8; }
    else if (off < 32768) { W = Wi_kj   + (size_t)b * 16384; rel = off - 16384;  NT = 8; }
    else if (off < 40960) { W = Wi_down + (size_t)b * 8192;  rel = off - 32768;  NT = 4; }
    else if (off < 49152) { W = Wi_up   + (size_t)b * 8192;  rel = off - 40960;  NT = 8; }
    else {
        const int i = (off - 49152) / 16384;
        rel = (off - 49152) % 16384;
        NT = 8;
        if (i == 2) W = Wi_lin + (size_t)b * 16384;
        else {
            const int idx = (i < 2) ? i : i - 1;
            W = Wi_res + (size_t)((b * 3 + idx / 2) * 2 + (idx & 1)) * 16384;
        }
    }
    const int j = rel & 7, lane = (rel >> 3) & 63, q = rel >> 9;
    const int nt = q % NT, kt = q / NT;
    const int k = kt * 32 + (lane >> 4) * 8 + j;
    const int n = nt * 16 + (lane & 15);
    const float x = W[(size_t)k * (NT * 16) + n];
    const unsigned short h = bf16_rn(x);
    wh[g] = (short)h;
    wl[g] = (short)bf16_rn(x - bf16_f(h));
}

// ---------------------------------------------------------------------------
// Both blocks' sbf projections in ONE pass over sbf
// ---------------------------------------------------------------------------
__global__ __launch_bounds__(256) void k_sbfproj2(
    const float* __restrict__ sbf, const float* __restrict__ W1a,
    const float* __restrict__ W1b, const int* __restrict__ rank,
    float* __restrict__ ta, float* __restrict__ tb)
{
    __shared__ float s_sbf[32 * SR];
    __shared__ float s_Wa[SR * BE];
    __shared__ float s_Wb[SR * BE];
    const int tid = threadIdx.x;
    const int t0  = blockIdx.x * 32;
    for (int i = tid; i < SR * BE; i += 256) { s_Wa[i] = W1a[i]; s_Wb[i] = W1b[i]; }
    const float* sb0 = sbf + (size_t)t0 * SR;
    for (int i = tid; i < 32 * SR; i += 256) s_sbf[i] = sb0[i];
    __syncthreads();
    const int tt = tid >> 3, j = tid & 7;
    float sa = 0.0f, sb = 0.0f;
    #pragma unroll
    for (int i = 0; i < SR; ++i) {
        const float v = s_sbf[tt * SR + i];
        sa = fmaf(v, s_Wa[i * BE + j], sa);
        sb = fmaf(v, s_Wb[i * BE + j], sb);
    }
    const size_t p = (size_t)rank[t0 + tt] * BE + j;
    ta[p] = sa;
    tb[p] = sb;
}

// ---------------------------------------------------------------------------
// MFMA fused front (64-row tile, split-bf16):
// p0 xji=silu(xe@Wji+b); p1 A<-silu(xe@Wkj+b).*rb; p2 down=silu(A@Wdown)
// ---------------------------------------------------------------------------
__global__ __launch_bounds__(256, 2) void k_front_mfma(
    const float* __restrict__ xe, const float* __restrict__ rbf,
    const short* __restrict__ wh, const short* __restrict__ wl,
    const float* __restrict__ bji, const float* __restrict__ bkj,
    const float* __restrict__ W1, const float* __restrict__ W2,
    float* __restrict__ xji, float* __restrict__ down)
{
    __shared__ short Ah[64 * 136];
    __shared__ short Al[64 * 136];
    __shared__ float s_tj[64 * 8];
    const int tid = threadIdx.x;
    const int r0  = blockIdx.x * 64;
    const int lane = tid & 63, wv = tid >> 6;
    const int lo4 = lane & 15, hi4 = lane >> 4;

    // stage xe (64 x 128 f32) -> split bf16 LDS
    {
        const float4* XG = reinterpret_cast<const float4*>(xe);
        for (int i = tid; i < 64 * 32; i += 256) {
            const int row = i >> 5, c4 = i & 31;
            const float4 v = XG[(size_t)(r0 + row) * 32 + c4];
            unsigned short h0 = bf16_rn(v.x), h1 = bf16_rn(v.y),
                           h2 = bf16_rn(v.z), h3 = bf16_rn(v.w);
            *reinterpret_cast<ushort4*>(&Ah[row * 136 + c4 * 4]) =
                make_ushort4(h0, h1, h2, h3);
            *reinterpret_cast<ushort4*>(&Al[row * 136 + c4 * 4]) =
                make_ushort4(bf16_rn(v.x - bf16_f(h0)), bf16_rn(v.y - bf16_f(h1)),
                             bf16_rn(v.z - bf16_f(h2)), bf16_rn(v.w - bf16_f(h3)));
        }
    }
    // tj[64][8] = rbf_tile @ W1
    for (int i = tid; i < 64 * 8; i += 256) {
        const int row = i >> 3, j = i & 7;
        const float* rr_ = rbf + (size_t)(r0 + row) * R;
        float s = 0.0f;
        #pragma unroll
        for (int q = 0; q < R; ++q) s = fmaf(rr_[q], W1[q * BE + j], s);
        s_tj[i] = s;
    }
    __syncthreads();

    f32x4 acc[4][2], car[4][2];

    auto gemm = [&](const short* Wh, const short* Wl) {   // N=128, K=128
        #pragma unroll
        for (int m = 0; m < 4; ++m)
            #pragma unroll
            for (int n = 0; n < 2; ++n) acc[m][n] = (f32x4)0.0f;
        for (int kt = 0; kt < 4; ++kt) {
            bf16x8 ahf[4], alf[4], bhf[2], blf[2];
            #pragma unroll
            for (int m = 0; m < 4; ++m) {
                const int off = (m * 16 + lo4) * 136 + kt * 32 + hi4 * 8;
                ahf[m] = *reinterpret_cast<const bf16x8*>(&Ah[off]);
                alf[m] = *reinterpret_cast<const bf16x8*>(&Al[off]);
            }
            #pragma unroll
            for (int n = 0; n < 2; ++n) {
                const size_t boff = ((size_t)((kt * 8 + wv * 2 + n) * 64) + lane) * 8;
                bhf[n] = *reinterpret_cast<const bf16x8*>(&Wh[boff]);
                blf[n] = *reinterpret_cast<const bf16x8*>(&Wl[boff]);
            }
            #pragma unroll
            for (int m = 0; m < 4; ++m)
                #pragma unroll
                for (int n = 0; n < 2; ++n) {
                    acc[m][n] = __builtin_amdgcn_mfma_f32_16x16x32_bf16(ahf[m], bhf[n], acc[m][n], 0, 0, 0);
                    acc[m][n] = __builtin_amdgcn_mfma_f32_16x16x32_bf16(ahf[m], blf[n], acc[m][n], 0, 0, 0);
                    acc[m][n] = __builtin_amdgcn_mfma_f32_16x16x32_bf16(alf[m], bhf[n], acc[m][n], 0, 0, 0);
                }
        }
    };

    // p0: xji = silu(xe@Wji + bji) -> global (f32)
    gemm(wh, wl);
    #pragma unroll
    for (int n = 0; n < 2; ++n) {
        const int col = (wv * 2 + n) * 16 + lo4;
        const float bb = bji[col];
        #pragma unroll
        for (int m = 0; m < 4; ++m)
            #pragma unroll
            for (int r = 0; r < 4; ++r) {
                const int row = r0 + m * 16 + hi4 * 4 + r;
                xji[(size_t)row * 128 + col] = silu_f(acc[m][n][r] + bb);
            }
    }

    // p1: car = silu(xe@Wkj + bkj) .* rb   (rb = tj @ W2, on the fly)
    gemm(wh + 16384, wl + 16384);
    {
        float w2c[2][8];
        #pragma unroll
        for (int n = 0; n < 2; ++n) {
            const int col = (wv * 2 + n) * 16 + lo4;
            #pragma unroll
            for (int j = 0; j < 8; ++j) w2c[n][j] = W2[j * 128 + col];
        }
        const float bb0 = bkj[(wv * 2 + 0) * 16 + lo4];
        const float bb1 = bkj[(wv * 2 + 1) * 16 + lo4];
        #pragma unroll
        for (int m = 0; m < 4; ++m)
            #pragma unroll
            for (int r = 0; r < 4; ++r) {
                const int row = m * 16 + hi4 * 4 + r;
                const float4 t0 = *reinterpret_cast<const float4*>(&s_tj[row * 8]);
                const float4 t1 = *reinterpret_cast<const float4*>(&s_tj[row * 8 + 4]);
                float rb0 = t0.x*w2c[0][0] + t0.y*w2c[0][1] + t0.z*w2c[0][2] + t0.w*w2c[0][3]
                          + t1.x*w2c[0][4] + t1.y*w2c[0][5] + t1.z*w2c[0][6] + t1.w*w2c[0][7];
                float rb1 = t0.x*w2c[1][0] + t0.y*w2c[1][1] + t0.z*w2c[1][2] + t0.w*w2c[1][3]
                          + t1.x*w2c[1][4] + t1.y*w2c[1][5] + t1.z*w2c[1][6] + t1.w*w2c[1][7];
                car[m][0][r] = silu_f(acc[m][0][r] + bb0) * rb0;
                car[m][1][r] = silu_f(acc[m][1][r] + bb1) * rb1;
            }
    }
    // write car back into split-bf16 A
    __syncthreads();
    #pragma unroll
    for (int m = 0; m < 4; ++m)
        #pragma unroll
        for (int n = 0; n < 2; ++n) {
            const int col = (wv * 2 + n) * 16 + lo4;
            #pragma unroll
            for (int r = 0; r < 4; ++r) {
                const int row = m * 16 + hi4 * 4 + r;
                const float x = car[m][n][r];
                const unsigned short h = bf16_rn(x);
                Ah[row * 136 + col] = (short)h;
                Al[row * 136 + col] = (short)bf16_rn(x - bf16_f(h));
            }
        }
    __syncthreads();

    // p2: down = silu(A @ Wdown)  (N=64: wave wv owns ntile wv)
    {
        const short* Wh = wh + 32768;
        const short* Wl = wl + 32768;
        f32x4 a2[4];
        #pragma unroll
        for (int m = 0; m < 4; ++m) a2[m] = (f32x4)0.0f;
        for (int kt = 0; kt < 4; ++kt) {
            bf16x8 ahf[4], alf[4], bhf, blf;
            #pragma unroll
            for (int m = 0; m < 4; ++m) {
                const int off = (m * 16 + lo4) * 136 + kt * 32 + hi4 * 8;
                ahf[m] = *reinterpret_cast<const bf16x8*>(&Ah[off]);
                alf[m] = *reinterpret_cast<const bf16x8*>(&Al[off]);
            }
            const size_t boff = ((size_t)((kt * 4 + wv) * 64) + lane) * 8;
            bhf = *reinterpret_cast<const bf16x8*>(&Wh[boff]);
            blf = *reinterpret_cast<const bf16x8*>(&Wl[boff]);
            #pragma unroll
            for (int m = 0; m < 4; ++m) {
                a2[m] = __builtin_amdgcn_mfma_f32_16x16x32_bf16(ahf[m], bhf, a2[m], 0, 0, 0);
                a2[m] = __builtin_amdgcn_mfma_f32_16x16x32_bf16(ahf[m], blf, a2[m], 0, 0, 0);
                a2[m] = __builtin_amdgcn_mfma_f32_16x16x32_bf16(alf[m], bhf, a2[m], 0, 0, 0);
            }
        }
        const int col = wv * 16 + lo4;
        #pragma unroll
        for (int m = 0; m < 4; ++m)
            #pragma unroll
            for (int r = 0; r < 4; ++r) {
                const int row = r0 + m * 16 + hi4 * 4 + r;
                down[(size_t)row * 64 + col] = silu_f(a2[m][r]);
            }
    }
}

// ---------------------------------------------------------------------------
// Edge aggregation over sorted triplets (one wave per edge)
// ---------------------------------------------------------------------------
__global__ __launch_bounds__(256) void k_agg(
    const int* __restrict__ rs, const int* __restrict__ kjs,
    const float* __restrict__ tmps, const float* __restrict__ down,
    const float* __restrict__ W2, float* __restrict__ agg)
{
    const int w = threadIdx.x >> 6, lane = threadIdx.x & 63;
    const int e = blockIdx.x * 4 + w;
    float w2[BE];
    #pragma unroll
    for (int j = 0; j < BE; ++j) w2[j] = W2[j * INTD + lane];

    const float4* tmps4 = reinterpret_cast<const float4*>(tmps);
    const int lo = rs[e], hi = rs[e + 1];
    float acc = 0.0f;
    int idx = lo;
    for (; idx + 1 < hi; idx += 2) {
        const int kja = kjs[idx], kjb = kjs[idx + 1];
        const float4 a0 = tmps4[2 * idx],     a1 = tmps4[2 * idx + 1];
        const float4 b0 = tmps4[2 * idx + 2], b1 = tmps4[2 * idx + 3];
        const float da = down[(size_t)kja * INTD + lane];
        const float db = down[(size_t)kjb * INTD + lane];
        float sa = a0.x * w2[0] + a0.y * w2[1] + a0.z * w2[2] + a0.w * w2[3]
                 + a1.x * w2[4] + a1.y * w2[5] + a1.z * w2[6] + a1.w * w2[7];
        float sb = b0.x * w2[0] + b0.y * w2[1] + b0.z * w2[2] + b0.w * w2[3]
                 + b1.x * w2[4] + b1.y * w2[5] + b1.z * w2[6] + b1.w * w2[7];
        acc = fmaf(da, sa, acc);
        acc = fmaf(db, sb, acc);
    }
    if (idx < hi) {
        const int kj = kjs[idx];
        const float4 a0 = tmps4[2 * idx], a1 = tmps4[2 * idx + 1];
        const float d = down[(size_t)kj * INTD + lane];
        float sa = a0.x * w2[0] + a0.y * w2[1] + a0.z * w2[2] + a0.w * w2[3]
                 + a1.x * w2[4] + a1.y * w2[5] + a1.z * w2[6] + a1.w * w2[7];
        acc = fmaf(d, sa, acc);
    }
    agg[(size_t)e * INTD + lane] = acc;
}

// ---------------------------------------------------------------------------
// MFMA fused tail (64-row tile, split-bf16)
// ---------------------------------------------------------------------------
__global__ __launch_bounds__(256, 2) void k_tail_mfma(
    const float* __restrict__ agg, const float* __restrict__ xji,
    const float* __restrict__ xe,
    const short* __restrict__ wh, const short* __restrict__ wl,
    const float* __restrict__ br, const float* __restrict__ blin,
    float* __restrict__ out)
{
    __shared__ short Ah[64 * 136];
    __shared__ short Al[64 * 136];
    const int tid = threadIdx.x;
    const int r0  = blockIdx.x * 64;
    const int lane = tid & 63, wv = tid >> 6;
    const int lo4 = lane & 15, hi4 = lane >> 4;

    {
        const float4* AG = reinterpret_cast<const float4*>(agg);
        for (int i = tid; i < 64 * 16; i += 256) {
            const int row = i >> 4, c4 = i & 15;
            const float4 v = AG[(size_t)(r0 + row) * 16 + c4];
            unsigned short h0 = bf16_rn(v.x), h1 = bf16_rn(v.y),
                           h2 = bf16_rn(v.z), h3 = bf16_rn(v.w);
            *reinterpret_cast<ushort4*>(&Ah[row * 136 + c4 * 4]) =
                make_ushort4(h0, h1, h2, h3);
            *reinterpret_cast<ushort4*>(&Al[row * 136 + c4 * 4]) =
                make_ushort4(bf16_rn(v.x - bf16_f(h0)), bf16_rn(v.y - bf16_f(h1)),
                             bf16_rn(v.z - bf16_f(h2)), bf16_rn(v.w - bf16_f(h3)));
        }
    }
    __syncthreads();

    f32x4 acc[4][2], car[4][2];

    auto gemm = [&](const short* Wh, const short* Wl, int nkt) {
        #pragma unroll
        for (int m = 0; m < 4; ++m)
            #pragma unroll
            for (int n = 0; n < 2; ++n) acc[m][n] = (f32x4)0.0f;
        for (int kt = 0; kt < nkt; ++kt) {
            bf16x8 ahf[4], alf[4], bhf[2], blf[2];
            #pragma unroll
            for (int m = 0; m < 4; ++m) {
                const int off = (m * 16 + lo4) * 136 + kt * 32 + hi4 * 8;
                ahf[m] = *reinterpret_cast<const bf16x8*>(&Ah[off]);
                alf[m] = *reinterpret_cast<const bf16x8*>(&Al[off]);
            }
            #pragma unroll
            for (int n = 0; n < 2; ++n) {
                const size_t boff = ((size_t)((kt * 8 + wv * 2 + n) * 64) + lane) * 8;
                bhf[n] = *reinterpret_cast<const bf16x8*>(&Wh[boff]);
                blf[n] = *reinterpret_cast<const bf16x8*>(&Wl[boff]);
            }
            #pragma unroll
            for (int m = 0; m < 4; ++m)
                #pragma unroll
                for (int n = 0; n < 2; ++n) {
                    acc[m][n] = __builtin_amdgcn_mfma_f32_16x16x32_bf16(ahf[m], bhf[n], acc[m][n], 0, 0, 0);
                    acc[m][n] = __builtin_amdgcn_mfma_f32_16x16x32_bf16(ahf[m], blf[n], acc[m][n], 0, 0, 0);
                    acc[m][n] = __builtin_amdgcn_mfma_f32_16x16x32_bf16(alf[m], bhf[n], acc[m][n], 0, 0, 0);
                }
        }
    };

    auto wrA = [&](f32x4 v[4][2]) {
        __syncthreads();
        #pragma unroll
        for (int m = 0; m < 4; ++m)
            #pragma unroll
            for (int n = 0; n < 2; ++n) {
                const int col = (wv * 2 + n) * 16 + lo4;
                #pragma unroll
                for (int r = 0; r < 4; ++r) {
                    const int row = m * 16 + hi4 * 4 + r;
                    const float x = v[m][n][r];
                    const unsigned short h = bf16_rn(x);
                    Ah[row * 136 + col] = (short)h;
                    Al[row * 136 + col] = (short)bf16_rn(x - bf16_f(h));
                }
            }
        __syncthreads();
    };

    // p0: car = silu(agg@Wup) + xji
    gemm(wh, wl, 2);
    #pragma unroll
    for (int m = 0; m < 4; ++m)
        #pragma unroll
        for (int n = 0; n < 2; ++n) {
            const int col = (wv * 2 + n) * 16 + lo4;
            #pragma unroll
            for (int r = 0; r < 4; ++r) {
                const int row = r0 + m * 16 + hi4 * 4 + r;
                car[m][n][r] = silu_f(acc[m][n][r]) + xji[(size_t)row * 128 + col];
            }
        }
    wrA(car);

    auto tphase = [&](const short* Wh, const short* Wl, const float* bias) {
        gemm(Wh, Wl, 4);
        #pragma unroll
        for (int m = 0; m < 4; ++m)
            #pragma unroll
            for (int n = 0; n < 2; ++n) {
                const float bb = bias[(wv * 2 + n) * 16 + lo4];
                #pragma unroll
                for (int r = 0; r < 4; ++r)
                    acc[m][n][r] = silu_f(acc[m][n][r] + bb);
            }
        wrA(acc);
    };
    auto cphase = [&](const short* Wh, const short* Wl, const float* bias) {
        gemm(Wh, Wl, 4);
        #pragma unroll
        for (int m = 0; m < 4; ++m)
            #pragma unroll
            for (int n = 0; n < 2; ++n) {
                const float bb = bias[(wv * 2 + n) * 16 + lo4];
                #pragma unroll
                for (int r = 0; r < 4; ++r)
                    car[m][n][r] += silu_f(acc[m][n][r] + bb);
            }
        wrA(car);
    };

    tphase(wh + 8192,              wl + 8192,              br + 0 * 128);   // W0
    cphase(wh + 8192 + 16384,      wl + 8192 + 16384,      br + 1 * 128);   // W1

    // p3: car = silu(acc + blin) + xe
    gemm(wh + 8192 + 2 * 16384, wl + 8192 + 2 * 16384, 4);
    #pragma unroll
    for (int m = 0; m < 4; ++m)
        #pragma unroll
        for (int n = 0; n < 2; ++n) {
            const int col = (wv * 2 + n) * 16 + lo4;
            const float bb = blin[col];
            #pragma unroll
            for (int r = 0; r < 4; ++r) {
                const int row = r0 + m * 16 + hi4 * 4 + r;
                car[m][n][r] = silu_f(acc[m][n][r] + bb) + xe[(size_t)row * 128 + col];
            }
        }
    wrA(car);

    tphase(wh + 8192 + 3 * 16384, wl + 8192 + 3 * 16384, br + 2 * 128);     // W2
    cphase(wh + 8192 + 4 * 16384, wl + 8192 + 4 * 16384, br + 3 * 128);     // W3
    tphase(wh + 8192 + 5 * 16384, wl + 8192 + 5 * 16384, br + 4 * 128);     // W4

    // p7: out = car + silu(acc + b5)
    gemm(wh + 8192 + 6 * 16384, wl + 8192 + 6 * 16384, 4);
    #pragma unroll
    for (int m = 0; m < 4; ++m)
        #pragma unroll
        for (int n = 0; n < 2; ++n) {
            const int col = (wv * 2 + n) * 16 + lo4;
            const float bb = br[5 * 128 + col];
            #pragma unroll
            for (int r = 0; r < 4; ++r) {
                const int row = r0 + m * 16 + hi4 * 4 + r;
                out[(size_t)row * 128 + col] = car[m][n][r] + silu_f(acc[m][n][r] + bb);
            }
        }
}

// ---------------------------------------------------------------------------
// Node aggregation (CSR over edge_i)
// ---------------------------------------------------------------------------
__global__ __launch_bounds__(256) void k_nodes(
    const int* __restrict__ rs, const int* __restrict__ perm,
    const float* __restrict__ rbf, const float* __restrict__ Wrbf,
    const float* __restrict__ xe, float* __restrict__ nodes)
{
    const int tid = threadIdx.x;
    const int n = blockIdx.x * 2 + (tid >> 7);
    const int c = tid & (H - 1);
    float wr[R];
    #pragma unroll
    for (int i = 0; i < R; ++i) wr[i] = Wrbf[i * H + c];
    float acc = 0.0f;
    const int lo = rs[n], hi = rs[n + 1];
    for (int idx = lo; idx < hi; ++idx) {
        const int e = perm[idx];
        const float* rb = rbf + (size_t)e * R;
        float g = 0.0f;
        #pragma unroll
        for (int i = 0; i < R; ++i) g = fmaf(rb[i], wr[i], g);
        acc = fmaf(g, xe[(size_t)e * H + c], acc);
    }
    nodes[(size_t)n * H + c] = acc;
}

// ---------------------------------------------------------------------------
// Fused output chain (f32)
// ---------------------------------------------------------------------------
__global__ __launch_bounds__(256) void k_outchain(
    const float* __restrict__ nodes, const float* __restrict__ Wup,
    const float* __restrict__ bup, const float* __restrict__ Wlin,
    const float* __restrict__ blin, const float* __restrict__ Wout,
    float* __restrict__ P)
{
    __shared__ float nb[16 * 132];
    __shared__ float hb[16 * 260];
    __shared__ float tbuf[16 * 260];
    __shared__ float red[64 * 16];
    const int tid = threadIdx.x;
    const int n0  = blockIdx.x * 16;
    float4* nb4 = reinterpret_cast<float4*>(nb);
    float4* hb4 = reinterpret_cast<float4*>(hb);
    float4* tb4 = reinterpret_cast<float4*>(tbuf);
    const float4* NG = reinterpret_cast<const float4*>(nodes);

    for (int i = tid; i < 16 * 32; i += 256) {
        int row = i >> 5, kk = i & 31;
        nb4[row * 33 + kk] = NG[(size_t)(n0 + row) * 32 + kk];
    }
    __syncthreads();

    const int cg = tid & 63, rq = tid >> 6, rbase = rq * 4;
    float acc[4][4];
    auto acc_bias = [&](const float* bias) {
        const float4 bv = reinterpret_cast<const float4*>(bias)[cg];
        #pragma unroll
        for (int r = 0; r < 4; ++r) { acc[r][0]=bv.x; acc[r][1]=bv.y; acc[r][2]=bv.z; acc[r][3]=bv.w; }
    };
    auto mm = [&](const float4* A4, const float4* W4, int K4, int AS4) {
        for (int k4 = 0; k4 < K4; ++k4) {
            const float4 wv0 = W4[(k4*4+0)*64 + cg];
            const float4 wv1 = W4[(k4*4+1)*64 + cg];
            const float4 wv2 = W4[(k4*4+2)*64 + cg];
            const float4 wv3 = W4[(k4*4+3)*64 + cg];
            #pragma unroll
            for (int r = 0; r < 4; ++r) {
                const float4 a = A4[(rbase + r) * AS4 + k4];
                acc[r][0]=fmaf(a.x,wv0.x,acc[r][0]); acc[r][1]=fmaf(a.x,wv0.y,acc[r][1]);
                acc[r][2]=fmaf(a.x,wv0.z,acc[r][2]); acc[r][3]=fmaf(a.x,wv0.w,acc[r][3]);
                acc[r][0]=fmaf(a.y,wv1.x,acc[r][0]); acc[r][1]=fmaf(a.y,wv1.y,acc[r][1]);
                acc[r][2]=fmaf(a.y,wv1.z,acc[r][2]); acc[r][3]=fmaf(a.y,wv1.w,acc[r][3]);
                acc[r][0]=fmaf(a.z,wv2.x,acc[r][0]); acc[r][1]=fmaf(a.z,wv2.y,acc[r][1]);
                acc[r][2]=fmaf(a.z,wv2.z,acc[r][2]); acc[r][3]=fmaf(a.z,wv2.w,acc[r][3]);
                acc[r][0]=fmaf(a.w,wv3.x,acc[r][0]); acc[r][1]=fmaf(a.w,wv3.y,acc[r][1]);
                acc[r][2]=fmaf(a.w,wv3.z,acc[r][2]); acc[r][3]=fmaf(a.w,wv3.w,acc[r][3]);
            }
        }
    };

    acc_bias(bup);
    mm(nb4, reinterpret_cast<const float4*>(Wup), 32, 33);
    #pragma unroll
    for (int r = 0; r < 4; ++r) hb4[(rbase + r) * 65 + cg] = make_float4(acc[r][0],acc[r][1],acc[r][2],acc[r][3]);
    __syncthreads();

    acc_bias(blin + 0 * OE);
    mm(hb4, reinterpret_cast<const float4*>(Wlin + 0 * OE * OE), 64, 65);
    #pragma unroll
    for (int r = 0; r < 4; ++r) tb4[(rbase + r) * 65 + cg] = silu4(make_float4(acc[r][0],acc[r][1],acc[r][2],acc[r][3]));
    __syncthreads();

    acc_bias(blin + 1 * OE);
    mm(tb4, reinterpret_cast<const float4*>(Wlin + 1 * OE * OE), 64, 65);
    #pragma unroll
    for (int r = 0; r < 4; ++r) hb4[(rbase + r) * 65 + cg] = silu4(make_float4(acc[r][0],acc[r][1],acc[r][2],acc[r][3]));
    __syncthreads();

    acc_bias(blin + 2 * OE);
    mm(hb4, reinterpret_cast<const float4*>(Wlin + 2 * OE * OE), 64, 65);
    #pragma unroll
    for (int r = 0; r < 4; ++r) tb4[(rbase + r) * 65 + cg] = silu4(make_float4(acc[r][0],acc[r][1],acc[r][2],acc[r][3]));
    __syncthreads();

    {
        const float4 wo = reinterpret_cast<const float4*>(Wout)[cg];
        #pragma unroll
        for (int r = 0; r < 4; ++r) {
            const int row = rbase + r;
            const float4 hv = tb4[row * 65 + cg];
            red[cg * 16 + row] = hv.x * wo.x + hv.y * wo.y + hv.z * wo.z + hv.w * wo.w;
        }
    }
    __syncthreads();
    if (tid < 16) {
        float s = 0.0f;
        for (int c = 0; c < 64; ++c) s += red[c * 16 + tid];
        P[n0 + tid] += s;
    }
}

// ---------------------------------------------------------------------------
extern "C" void kernel_launch(void* const* d_in, const int* in_sizes, int n_in,
                              void* d_out, int out_size, void* d_ws, size_t ws_size,
                              hipStream_t stream)
{
    (void)in_sizes; (void)n_in; (void)out_size; (void)ws_size;

    const float* x       = (const float*)d_in[0];
    const float* dist    = (const float*)d_in[1];
    const float* freq    = (const float*)d_in[2];
    const float* sbf     = (const float*)d_in[3];
    const int*   idx_kj  = (const int*)d_in[4];
    const int*   idx_ji  = (const int*)d_in[5];
    const int*   edge_i  = (const int*)d_in[6];
    const float* Wi_rbf1 = (const float*)d_in[8];
    const float* Wi_rbf2 = (const float*)d_in[9];
    const float* Wi_sbf1 = (const float*)d_in[10];
    const float* Wi_sbf2 = (const float*)d_in[11];
    const float* Wi_kj   = (const float*)d_in[12];
    const float* bi_kj   = (const float*)d_in[13];
    const float* Wi_ji   = (const float*)d_in[14];
    const float* bi_ji   = (const float*)d_in[15];
    const float* Wi_down = (const float*)d_in[16];
    const float* Wi_up   = (const float*)d_in[17];
    const float* Wi_res  = (const float*)d_in[18];
    const float* bi_res  = (const float*)d_in[19];
    const float* Wi_lin  = (const float*)d_in[20];
    const float* bi_lin  = (const float*)d_in[21];
    const float* Wo_rbf  = (const float*)d_in[22];
    const float* Wo_up   = (const float*)d_in[23];
    const float* bo_up   = (const float*)d_in[24];
    const float* Wo_lin  = (const float*)d_in[25];
    const float* bo_lin  = (const float*)d_in[26];
    const float* Wo_out  = (const float*)d_in[27];
    float* P = (float*)d_out;

    // ---- workspace carve-up ----
    float* w      = (float*)d_ws;
    float* rbf    = w;  w += (size_t)E * R;
    float* xeA    = w;  w += (size_t)E * H;
    float* xeB    = w;  w += (size_t)E * H;
    float* xji    = w;  w += (size_t)E * H;
    float* down   = w;  w += (size_t)E * INTD;
    float* agg    = w;  w += (size_t)E * INTD;
    float* tmp0   = w;  w += (size_t)T * BE;
    float* tmp1   = w;  w += (size_t)T * BE;
    float* nodes  = w;  w += (size_t)NN * H;
    int* ip       = (int*)w;
    int* trip_rs  = ip;  ip += E + 1;
    int* trip_cur = ip;  ip += E;
    int* rank_t   = ip;  ip += T;
    int* kjs      = ip;  ip += T;
    int* edge_rs  = ip;  ip += NN + 1;
    int* edge_cur = ip;  ip += NN;
    int* perm_e   = ip;  ip += E;
    int* bsumT    = ip;  ip += 64;
    int* bsumE    = ip;  ip += 64;
    short* wpk_hi = (short*)ip;
    short* wpk_lo = wpk_hi + 2 * PKB;

    // ---- CSR build ----
    hipMemsetAsync(trip_cur, 0, (size_t)E * sizeof(int), stream);
    hipMemsetAsync(edge_cur, 0, (size_t)NN * sizeof(int), stream);
    k_count<<<(T + 255) / 256, 256, 0, stream>>>(idx_ji, T, trip_cur);
    k_count<<<(E + 255) / 256, 256, 0, stream>>>(edge_i, E, edge_cur);
    const int nbT = (E + 2047) / 2048, nbE = (NN + 2047) / 2048;
    k_red<<<nbT, 256, 0, stream>>>(trip_cur, E, bsumT);
    k_scanb<<<1, 64, 0, stream>>>(bsumT, nbT);
    k_fill_rs<<<nbT, 256, 0, stream>>>(trip_cur, E, bsumT, trip_rs, trip_cur);
    k_red<<<nbE, 256, 0, stream>>>(edge_cur, NN, bsumE);
    k_scanb<<<1, 64, 0, stream>>>(bsumE, nbE);
    k_fill_rs<<<nbE, 256, 0, stream>>>(edge_cur, NN, bsumE, edge_rs, edge_cur);
    k_fill_trip<<<(T + 255) / 256, 256, 0, stream>>>(idx_ji, idx_kj, T, trip_cur, kjs, rank_t);
    k_fill<<<(E + 255) / 256, 256, 0, stream>>>(edge_i, E, edge_cur, perm_e);

    hipMemsetAsync(d_out, 0, (size_t)NN * sizeof(float), stream);
    k_rbf<<<(E + 255) / 256, 256, 0, stream>>>(dist, freq, rbf);
    k_pack<<<(2 * PKB + 255) / 256, 256, 0, stream>>>(Wi_ji, Wi_kj, Wi_down,
                                                      Wi_up, Wi_res, Wi_lin,
                                                      wpk_hi, wpk_lo);
    k_sbfproj2<<<T / 32, 256, 0, stream>>>(sbf, Wi_sbf1, Wi_sbf1 + (size_t)SR * BE,
                                           rank_t, tmp0, tmp1);

    auto out_block = [&](int b, const float* xe) {
        k_nodes<<<NN / 2, 256, 0, stream>>>(edge_rs, perm_e, rbf,
                                            Wo_rbf + (size_t)b * R * H, xe, nodes);
        k_outchain<<<NN / 16, 256, 0, stream>>>(nodes,
                                                Wo_up + (size_t)b * H * OE,
                                                bo_up + (size_t)b * OE,
                                                Wo_lin + (size_t)b * 3 * OE * OE,
                                                bo_lin + (size_t)b * 3 * OE,
                                                Wo_out + (size_t)b * OE, P);
    };

    const int gE64 = E / 64;
    auto interact = [&](int b, const float* xe, const float* tmp, float* out) {
        k_front_mfma<<<gE64, 256, 0, stream>>>(xe, rbf,
                                               wpk_hi + (size_t)b * PKB,
                                               wpk_lo + (size_t)b * PKB,
                                               bi_ji + (size_t)b * H,
                                               bi_kj + (size_t)b * H,
                                               Wi_rbf1 + (size_t)b * R * BE,
                                               Wi_rbf2 + (size_t)b * BE * H,
                                               xji, down);
        k_agg<<<E / 4, 256, 0, stream>>>(trip_rs, kjs, tmp, down,
                                         Wi_sbf2 + (size_t)b * BE * INTD, agg);
        k_tail_mfma<<<gE64, 256, 0, stream>>>(agg, xji, xe,
                                              wpk_hi + (size_t)b * PKB + TAILO,
                                              wpk_lo + (size_t)b * PKB + TAILO,
                                              bi_res + (size_t)b * 3 * 2 * H,
                                              bi_lin + (size_t)b * H, out);
    };

    out_block(0, x);
    interact(0, x, tmp0, xeB);
    out_block(1, xeB);
    interact(1, xeB, tmp1, xeA);
    out_block(2, xeA);
}

// Round 9
// 1347.097 us; speedup vs baseline: 1.8199x; 1.1032x over previous
//
#include <hip/hip_runtime.h>
#include <hip/hip_bf16.h>

// DimeNet++ forward: k_front + k_tail on MFMA (split-bf16, operand-swapped:
// weights as A, activations as B -> C holds 4 contiguous features/lane).
namespace {
constexpr int E     = 120000;
constexpr int T     = 800000;
constexpr int NN    = 12000;
constexpr int H     = 128;
constexpr int INTD  = 64;
constexpr int BE    = 8;
constexpr int R     = 6;
constexpr int SR    = 42;
constexpr int OE    = 256;
constexpr float CUTOFF = 5.0f;
// packed weights per interaction block:
// [Wji 16384 | Wkj 16384 | Wdown 8192 | Wup 8192 | W0 W1 Wlin W2 W3 W4 W5 7x16384]
constexpr int PKB   = 163840;
constexpr int TAILO = 40960;   // tail base offset within a block
}

typedef __attribute__((ext_vector_type(8))) short bf16x8;
typedef __attribute__((ext_vector_type(4))) float f32x4;

__device__ __forceinline__ float silu_f(float x) { return x / (1.0f + __expf(-x)); }
__device__ __forceinline__ float4 silu4(float4 v) {
    return make_float4(silu_f(v.x), silu_f(v.y), silu_f(v.z), silu_f(v.w));
}

__device__ __forceinline__ unsigned fbits(float x) {
    union { float f; unsigned u; } v; v.f = x; return v.u;
}
__device__ __forceinline__ float fof(unsigned u) {
    union { float f; unsigned u; } v; v.u = u; return v.f;
}
__device__ __forceinline__ unsigned short bf16_rn(float x) {
    unsigned u = fbits(x);
    unsigned r = u + 0x7FFFu + ((u >> 16) & 1u);
    return (unsigned short)(r >> 16);
}
__device__ __forceinline__ float bf16_f(unsigned short h) { return fof(((unsigned)h) << 16); }

// truncation split: x = hi + lo (hi = mantissa-truncated bf16, lo compensates);
// packs two elements' hi shorts into h, lo shorts into l.
__device__ __forceinline__ void pack2(float x0, float x1, unsigned& h, unsigned& l) {
    const unsigned u0 = fbits(x0), u1 = fbits(x1);
    const unsigned t0 = u0 & 0xFFFF0000u, t1 = u1 & 0xFFFF0000u;
    h = (u0 >> 16) | t1;
    l = (fbits(x0 - fof(t0)) >> 16) | (fbits(x1 - fof(t1)) & 0xFFFF0000u);
}

// ---------------------------------------------------------------------------
// rbf[E,6]
// ---------------------------------------------------------------------------
__global__ void k_rbf(const float* __restrict__ dist, const float* __restrict__ freq,
                      float* __restrict__ rbf) {
    int e = blockIdx.x * blockDim.x + threadIdx.x;
    if (e >= E) return;
    float d  = dist[e] * (1.0f / CUTOFF);
    float d2 = d * d;
    float d5 = d2 * d2 * d;
    float env = 1.0f / d - 28.0f * d5 + 48.0f * d5 * d - 21.0f * d5 * d2;
    #pragma unroll
    for (int i = 0; i < R; ++i) rbf[e * R + i] = env * sinf(freq[i] * d);
}

// ---------------------------------------------------------------------------
// CSR build
// ---------------------------------------------------------------------------
__global__ void k_count(const int* __restrict__ idx, int n, int* __restrict__ cnt) {
    int i = blockIdx.x * 256 + threadIdx.x;
    if (i < n) atomicAdd(&cnt[idx[i]], 1);
}

__global__ __launch_bounds__(256) void k_red(const int* __restrict__ cnt, int n,
                                             int* __restrict__ bsum) {
    __shared__ int ws[4];
    const int tid = threadIdx.x;
    const int base = blockIdx.x * 2048 + tid * 8;
    int s = 0;
    #pragma unroll
    for (int k = 0; k < 8; ++k) { int i = base + k; s += (i < n) ? cnt[i] : 0; }
    #pragma unroll
    for (int off = 32; off; off >>= 1) s += __shfl_down(s, off);
    if ((tid & 63) == 0) ws[tid >> 6] = s;
    __syncthreads();
    if (tid == 0) bsum[blockIdx.x] = ws[0] + ws[1] + ws[2] + ws[3];
}

__global__ void k_scanb(int* __restrict__ b, int nb) {   // nb <= 64
    __shared__ int s[64];
    const int tid = threadIdx.x;
    if (tid < nb) s[tid] = b[tid];
    __syncthreads();
    if (tid == 0) {
        int run = 0;
        for (int i = 0; i < nb; ++i) { int c = s[i]; s[i] = run; run += c; }
    }
    __syncthreads();
    if (tid < nb) b[tid] = s[tid];
}

__global__ __launch_bounds__(256) void k_fill_rs(const int* __restrict__ cnt, int n,
                                                 const int* __restrict__ boff,
                                                 int* __restrict__ rs, int* __restrict__ cur) {
    __shared__ int ts[256];
    const int tid = threadIdx.x;
    const int base = blockIdx.x * 2048 + tid * 8;
    int v[8]; int s = 0;
    #pragma unroll
    for (int k = 0; k < 8; ++k) { int i = base + k; v[k] = (i < n) ? cnt[i] : 0; s += v[k]; }
    ts[tid] = s;
    __syncthreads();
    for (int off = 1; off < 256; off <<= 1) {
        int t = (tid >= off) ? ts[tid - off] : 0;
        __syncthreads();
        ts[tid] += t;
        __syncthreads();
    }
    int ex = boff[blockIdx.x] + ((tid == 0) ? 0 : ts[tid - 1]);
    #pragma unroll
    for (int k = 0; k < 8; ++k) {
        int i = base + k;
        if (i < n) {
            rs[i] = ex; cur[i] = ex; ex += v[k];
            if (i == n - 1) rs[n] = ex;
        }
    }
}

__global__ void k_fill(const int* __restrict__ idx, int n, int* __restrict__ cur,
                       int* __restrict__ perm) {
    int i = blockIdx.x * 256 + threadIdx.x;
    if (i < n) perm[atomicAdd(&cur[idx[i]], 1)] = i;
}

__global__ void k_fill_trip(const int* __restrict__ idx_ji, const int* __restrict__ idx_kj,
                            int n, int* __restrict__ cur,
                            int* __restrict__ kjs, int* __restrict__ rank) {
    int i = blockIdx.x * 256 + threadIdx.x;
    if (i < n) {
        int pos = atomicAdd(&cur[idx_ji[i]], 1);
        kjs[pos] = idx_kj[i];
        rank[i]  = pos;
    }
}

// ---------------------------------------------------------------------------
// Pack all interaction weights into MFMA fragment order, split bf16.
// Element (kt,nt,lane,j) <- W[kt*32 + (lane>>4)*8 + j][nt*16 + (lane&15)]
// (valid as B-frag of W, and as A-frag of W^T — layouts are symmetric)
// ---------------------------------------------------------------------------
__global__ __launch_bounds__(256) void k_pack(
    const float* __restrict__ Wi_ji, const float* __restrict__ Wi_kj,
    const float* __restrict__ Wi_down,
    const float* __restrict__ Wi_up, const float* __restrict__ Wi_res,
    const float* __restrict__ Wi_lin,
    short* __restrict__ wh, short* __restrict__ wl)
{
    const int g = blockIdx.x * 256 + threadIdx.x;
    if (g >= 2 * PKB) return;
    const int b = g / PKB;
    const int off = g % PKB;
    const float* W;
    int rel, NT;
    if (off < 16384)      { W = Wi_ji   + (size_t)b * 16384; rel = off;          NT = 8; }
    else if (off < 32768) { W = Wi_kj   + (size_t)b * 16384; rel = off - 16384;  NT = 8; }
    else if (off < 40960) { W = Wi_down + (size_t)b * 8192;  rel = off - 32768;  NT = 4; }
    else if (off < 49152) { W = Wi_up   + (size_t)b * 8192;  rel = off - 40960;  NT = 8; }
    else {
        const int i = (off - 49152) / 16384;
        rel = (off - 49152) % 16384;
        NT = 8;
        if (i == 2) W = Wi_lin + (size_t)b * 16384;
        else {
            const int idx = (i < 2) ? i : i - 1;
            W = Wi_res + (size_t)((b * 3 + idx / 2) * 2 + (idx & 1)) * 16384;
        }
    }
    const int j = rel & 7, lane = (rel >> 3) & 63, q = rel >> 9;
    const int nt = q % NT, kt = q / NT;
    const int k = kt * 32 + (lane >> 4) * 8 + j;
    const int n = nt * 16 + (lane & 15);
    const float x = W[(size_t)k * (NT * 16) + n];
    const unsigned short h = bf16_rn(x);
    wh[g] = (short)h;
    wl[g] = (short)bf16_rn(x - bf16_f(h));
}

// ---------------------------------------------------------------------------
// Both blocks' sbf projections in ONE pass over sbf
// ---------------------------------------------------------------------------
__global__ __launch_bounds__(256) void k_sbfproj2(
    const float* __restrict__ sbf, const float* __restrict__ W1a,
    const float* __restrict__ W1b, const int* __restrict__ rank,
    float* __restrict__ ta, float* __restrict__ tb)
{
    __shared__ float s_sbf[32 * SR];
    __shared__ float s_Wa[SR * BE];
    __shared__ float s_Wb[SR * BE];
    const int tid = threadIdx.x;
    const int t0  = blockIdx.x * 32;
    for (int i = tid; i < SR * BE; i += 256) { s_Wa[i] = W1a[i]; s_Wb[i] = W1b[i]; }
    const float* sb0 = sbf + (size_t)t0 * SR;
    for (int i = tid; i < 32 * SR; i += 256) s_sbf[i] = sb0[i];
    __syncthreads();
    const int tt = tid >> 3, j = tid & 7;
    float sa = 0.0f, sb = 0.0f;
    #pragma unroll
    for (int i = 0; i < SR; ++i) {
        const float v = s_sbf[tt * SR + i];
        sa = fmaf(v, s_Wa[i * BE + j], sa);
        sb = fmaf(v, s_Wb[i * BE + j], sb);
    }
    const size_t p = (size_t)rank[t0 + tt] * BE + j;
    ta[p] = sa;
    tb[p] = sb;
}

// ---------------------------------------------------------------------------
// MFMA fused front (64-row tile, split-bf16, operand-swapped):
// p0 xji=silu(xe@Wji+b); p1 A<-silu(xe@Wkj+b).*rb; p2 down=silu(A@Wdown)
// ---------------------------------------------------------------------------
__global__ __launch_bounds__(256, 2) void k_front_mfma(
    const float* __restrict__ xe, const float* __restrict__ rbf,
    const short* __restrict__ wh, const short* __restrict__ wl,
    const float* __restrict__ bji, const float* __restrict__ bkj,
    const float* __restrict__ W1, const float* __restrict__ W2,
    float* __restrict__ xji, float* __restrict__ down)
{
    __shared__ short Ah[64 * 136];
    __shared__ short Al[64 * 136];
    __shared__ float s_tj[64 * 8];
    const int tid = threadIdx.x;
    const int r0  = blockIdx.x * 64;
    const int lane = tid & 63, wv = tid >> 6;
    const int lo4 = lane & 15, hi4 = lane >> 4;

    // stage xe (64 x 128 f32) -> truncation-split bf16 LDS
    {
        const float4* XG = reinterpret_cast<const float4*>(xe);
        for (int i = tid; i < 64 * 32; i += 256) {
            const int row = i >> 5, c4 = i & 31;
            const float4 v = XG[(size_t)(r0 + row) * 32 + c4];
            unsigned h0, l0, h1, l1;
            pack2(v.x, v.y, h0, l0);
            pack2(v.z, v.w, h1, l1);
            *reinterpret_cast<uint2*>(&Ah[row * 136 + c4 * 4]) = make_uint2(h0, h1);
            *reinterpret_cast<uint2*>(&Al[row * 136 + c4 * 4]) = make_uint2(l0, l1);
        }
    }
    // tj[64][8] = rbf_tile @ W1
    for (int i = tid; i < 64 * 8; i += 256) {
        const int row = i >> 3, j = i & 7;
        const float* rr_ = rbf + (size_t)(r0 + row) * R;
        float s = 0.0f;
        #pragma unroll
        for (int q = 0; q < R; ++q) s = fmaf(rr_[q], W1[q * BE + j], s);
        s_tj[i] = s;
    }
    __syncthreads();

    f32x4 acc[4][2], car[4][2];

    // D = W^T X^T: weights as A, acts as B. Output: col=edge(lo4), row=feature.
    auto gemm = [&](const short* Wh, const short* Wl) {   // 128 out-feats, K=128
        #pragma unroll
        for (int m = 0; m < 4; ++m)
            #pragma unroll
            for (int n = 0; n < 2; ++n) acc[m][n] = (f32x4)0.0f;
        for (int kt = 0; kt < 4; ++kt) {
            bf16x8 xh[4], xl[4], whf[2], wlf[2];
            #pragma unroll
            for (int m = 0; m < 4; ++m) {
                const int off = (m * 16 + lo4) * 136 + kt * 32 + hi4 * 8;
                xh[m] = *reinterpret_cast<const bf16x8*>(&Ah[off]);
                xl[m] = *reinterpret_cast<const bf16x8*>(&Al[off]);
            }
            #pragma unroll
            for (int n = 0; n < 2; ++n) {
                const size_t boff = ((size_t)((kt * 8 + wv * 2 + n) * 64) + lane) * 8;
                whf[n] = *reinterpret_cast<const bf16x8*>(&Wh[boff]);
                wlf[n] = *reinterpret_cast<const bf16x8*>(&Wl[boff]);
            }
            #pragma unroll
            for (int m = 0; m < 4; ++m)
                #pragma unroll
                for (int n = 0; n < 2; ++n) {
                    acc[m][n] = __builtin_amdgcn_mfma_f32_16x16x32_bf16(whf[n], xh[m], acc[m][n], 0, 0, 0);
                    acc[m][n] = __builtin_amdgcn_mfma_f32_16x16x32_bf16(wlf[n], xh[m], acc[m][n], 0, 0, 0);
                    acc[m][n] = __builtin_amdgcn_mfma_f32_16x16x32_bf16(whf[n], xl[m], acc[m][n], 0, 0, 0);
                }
        }
    };

    // p0: xji = silu(xe@Wji + bji) -> global (float4 per lane)
    gemm(wh, wl);
    #pragma unroll
    for (int n = 0; n < 2; ++n) {
        const int feat0 = (wv * 2 + n) * 16 + hi4 * 4;
        const float4 bj = *reinterpret_cast<const float4*>(&bji[feat0]);
        #pragma unroll
        for (int m = 0; m < 4; ++m) {
            const int edge = r0 + m * 16 + lo4;
            float4 o = make_float4(silu_f(acc[m][n][0] + bj.x), silu_f(acc[m][n][1] + bj.y),
                                   silu_f(acc[m][n][2] + bj.z), silu_f(acc[m][n][3] + bj.w));
            *reinterpret_cast<float4*>(&xji[(size_t)edge * 128 + feat0]) = o;
        }
    }

    // p1: car = silu(xe@Wkj + bkj) .* rb   (rb = tj @ W2 per feature)
    gemm(wh + 16384, wl + 16384);
    #pragma unroll
    for (int n = 0; n < 2; ++n) {
        const int feat0 = (wv * 2 + n) * 16 + hi4 * 4;
        const float4 bk = *reinterpret_cast<const float4*>(&bkj[feat0]);
        float4 w2v[8];
        #pragma unroll
        for (int j = 0; j < 8; ++j)
            w2v[j] = *reinterpret_cast<const float4*>(&W2[j * 128 + feat0]);
        #pragma unroll
        for (int m = 0; m < 4; ++m) {
            const int erow = m * 16 + lo4;
            const float4 t0 = *reinterpret_cast<const float4*>(&s_tj[erow * 8]);
            const float4 t1 = *reinterpret_cast<const float4*>(&s_tj[erow * 8 + 4]);
            float rb0 = 0, rb1 = 0, rb2 = 0, rb3 = 0;
            const float tj[8] = {t0.x, t0.y, t0.z, t0.w, t1.x, t1.y, t1.z, t1.w};
            #pragma unroll
            for (int j = 0; j < 8; ++j) {
                rb0 = fmaf(tj[j], w2v[j].x, rb0); rb1 = fmaf(tj[j], w2v[j].y, rb1);
                rb2 = fmaf(tj[j], w2v[j].z, rb2); rb3 = fmaf(tj[j], w2v[j].w, rb3);
            }
            car[m][n][0] = silu_f(acc[m][n][0] + bk.x) * rb0;
            car[m][n][1] = silu_f(acc[m][n][1] + bk.y) * rb1;
            car[m][n][2] = silu_f(acc[m][n][2] + bk.z) * rb2;
            car[m][n][3] = silu_f(acc[m][n][3] + bk.w) * rb3;
        }
    }
    // write car back into split-bf16 A (packed b64 writes)
    __syncthreads();
    #pragma unroll
    for (int m = 0; m < 4; ++m) {
        const int edge = m * 16 + lo4;
        #pragma unroll
        for (int n = 0; n < 2; ++n) {
            const int feat0 = (wv * 2 + n) * 16 + hi4 * 4;
            unsigned h0, l0, h1, l1;
            pack2(car[m][n][0], car[m][n][1], h0, l0);
            pack2(car[m][n][2], car[m][n][3], h1, l1);
            *reinterpret_cast<uint2*>(&Ah[edge * 136 + feat0]) = make_uint2(h0, h1);
            *reinterpret_cast<uint2*>(&Al[edge * 136 + feat0]) = make_uint2(l0, l1);
        }
    }
    __syncthreads();

    // p2: down = silu(A @ Wdown)  (64 out-feats: wave wv owns feature tile wv)
    {
        const short* Wh = wh + 32768;
        const short* Wl = wl + 32768;
        f32x4 a2[4];
        #pragma unroll
        for (int m = 0; m < 4; ++m) a2[m] = (f32x4)0.0f;
        for (int kt = 0; kt < 4; ++kt) {
            bf16x8 xh[4], xl[4], whf, wlf;
            #pragma unroll
            for (int m = 0; m < 4; ++m) {
                const int off = (m * 16 + lo4) * 136 + kt * 32 + hi4 * 8;
                xh[m] = *reinterpret_cast<const bf16x8*>(&Ah[off]);
                xl[m] = *reinterpret_cast<const bf16x8*>(&Al[off]);
            }
            const size_t boff = ((size_t)((kt * 4 + wv) * 64) + lane) * 8;
            whf = *reinterpret_cast<const bf16x8*>(&Wh[boff]);
            wlf = *reinterpret_cast<const bf16x8*>(&Wl[boff]);
            #pragma unroll
            for (int m = 0; m < 4; ++m) {
                a2[m] = __builtin_amdgcn_mfma_f32_16x16x32_bf16(whf, xh[m], a2[m], 0, 0, 0);
                a2[m] = __builtin_amdgcn_mfma_f32_16x16x32_bf16(wlf, xh[m], a2[m], 0, 0, 0);
                a2[m] = __builtin_amdgcn_mfma_f32_16x16x32_bf16(whf, xl[m], a2[m], 0, 0, 0);
            }
        }
        const int feat0 = wv * 16 + hi4 * 4;
        #pragma unroll
        for (int m = 0; m < 4; ++m) {
            const int edge = r0 + m * 16 + lo4;
            *reinterpret_cast<float4*>(&down[(size_t)edge * 64 + feat0]) =
                make_float4(silu_f(a2[m][0]), silu_f(a2[m][1]),
                            silu_f(a2[m][2]), silu_f(a2[m][3]));
        }
    }
}

// ---------------------------------------------------------------------------
// Edge aggregation over sorted triplets (one wave per edge)
// ---------------------------------------------------------------------------
__global__ __launch_bounds__(256) void k_agg(
    const int* __restrict__ rs, const int* __restrict__ kjs,
    const float* __restrict__ tmps, const float* __restrict__ down,
    const float* __restrict__ W2, float* __restrict__ agg)
{
    const int w = threadIdx.x >> 6, lane = threadIdx.x & 63;
    const int e = blockIdx.x * 4 + w;
    float w2[BE];
    #pragma unroll
    for (int j = 0; j < BE; ++j) w2[j] = W2[j * INTD + lane];

    const float4* tmps4 = reinterpret_cast<const float4*>(tmps);
    const int lo = rs[e], hi = rs[e + 1];
    float acc = 0.0f;
    int idx = lo;
    for (; idx + 1 < hi; idx += 2) {
        const int kja = kjs[idx], kjb = kjs[idx + 1];
        const float4 a0 = tmps4[2 * idx],     a1 = tmps4[2 * idx + 1];
        const float4 b0 = tmps4[2 * idx + 2], b1 = tmps4[2 * idx + 3];
        const float da = down[(size_t)kja * INTD + lane];
        const float db = down[(size_t)kjb * INTD + lane];
        float sa = a0.x * w2[0] + a0.y * w2[1] + a0.z * w2[2] + a0.w * w2[3]
                 + a1.x * w2[4] + a1.y * w2[5] + a1.z * w2[6] + a1.w * w2[7];
        float sb = b0.x * w2[0] + b0.y * w2[1] + b0.z * w2[2] + b0.w * w2[3]
                 + b1.x * w2[4] + b1.y * w2[5] + b1.z * w2[6] + b1.w * w2[7];
        acc = fmaf(da, sa, acc);
        acc = fmaf(db, sb, acc);
    }
    if (idx < hi) {
        const int kj = kjs[idx];
        const float4 a0 = tmps4[2 * idx], a1 = tmps4[2 * idx + 1];
        const float d = down[(size_t)kj * INTD + lane];
        float sa = a0.x * w2[0] + a0.y * w2[1] + a0.z * w2[2] + a0.w * w2[3]
                 + a1.x * w2[4] + a1.y * w2[5] + a1.z * w2[6] + a1.w * w2[7];
        acc = fmaf(d, sa, acc);
    }
    agg[(size_t)e * INTD + lane] = acc;
}

// ---------------------------------------------------------------------------
// MFMA fused tail (64-row tile, split-bf16, operand-swapped)
// ---------------------------------------------------------------------------
__global__ __launch_bounds__(256, 2) void k_tail_mfma(
    const float* __restrict__ agg, const float* __restrict__ xji,
    const float* __restrict__ xe,
    const short* __restrict__ wh, const short* __restrict__ wl,
    const float* __restrict__ br, const float* __restrict__ blin,
    float* __restrict__ out)
{
    __shared__ short Ah[64 * 136];
    __shared__ short Al[64 * 136];
    const int tid = threadIdx.x;
    const int r0  = blockIdx.x * 64;
    const int lane = tid & 63, wv = tid >> 6;
    const int lo4 = lane & 15, hi4 = lane >> 4;

    // stage agg (64 x 64 f32) -> truncation-split bf16 LDS
    {
        const float4* AG = reinterpret_cast<const float4*>(agg);
        for (int i = tid; i < 64 * 16; i += 256) {
            const int row = i >> 4, c4 = i & 15;
            const float4 v = AG[(size_t)(r0 + row) * 16 + c4];
            unsigned h0, l0, h1, l1;
            pack2(v.x, v.y, h0, l0);
            pack2(v.z, v.w, h1, l1);
            *reinterpret_cast<uint2*>(&Ah[row * 136 + c4 * 4]) = make_uint2(h0, h1);
            *reinterpret_cast<uint2*>(&Al[row * 136 + c4 * 4]) = make_uint2(l0, l1);
        }
    }
    __syncthreads();

    f32x4 acc[4][2], car[4][2];

    auto gemm = [&](const short* Wh, const short* Wl, int nkt) {
        #pragma unroll
        for (int m = 0; m < 4; ++m)
            #pragma unroll
            for (int n = 0; n < 2; ++n) acc[m][n] = (f32x4)0.0f;
        for (int kt = 0; kt < nkt; ++kt) {
            bf16x8 xh[4], xl[4], whf[2], wlf[2];
            #pragma unroll
            for (int m = 0; m < 4; ++m) {
                const int off = (m * 16 + lo4) * 136 + kt * 32 + hi4 * 8;
                xh[m] = *reinterpret_cast<const bf16x8*>(&Ah[off]);
                xl[m] = *reinterpret_cast<const bf16x8*>(&Al[off]);
            }
            #pragma unroll
            for (int n = 0; n < 2; ++n) {
                const size_t boff = ((size_t)((kt * 8 + wv * 2 + n) * 64) + lane) * 8;
                whf[n] = *reinterpret_cast<const bf16x8*>(&Wh[boff]);
                wlf[n] = *reinterpret_cast<const bf16x8*>(&Wl[boff]);
            }
            #pragma unroll
            for (int m = 0; m < 4; ++m)
                #pragma unroll
                for (int n = 0; n < 2; ++n) {
                    acc[m][n] = __builtin_amdgcn_mfma_f32_16x16x32_bf16(whf[n], xh[m], acc[m][n], 0, 0, 0);
                    acc[m][n] = __builtin_amdgcn_mfma_f32_16x16x32_bf16(wlf[n], xh[m], acc[m][n], 0, 0, 0);
                    acc[m][n] = __builtin_amdgcn_mfma_f32_16x16x32_bf16(whf[n], xl[m], acc[m][n], 0, 0, 0);
                }
        }
    };

    auto wrA = [&](f32x4 v[4][2]) {
        __syncthreads();
        #pragma unroll
        for (int m = 0; m < 4; ++m) {
            const int edge = m * 16 + lo4;
            #pragma unroll
            for (int n = 0; n < 2; ++n) {
                const int feat0 = (wv * 2 + n) * 16 + hi4 * 4;
                unsigned h0, l0, h1, l1;
                pack2(v[m][n][0], v[m][n][1], h0, l0);
                pack2(v[m][n][2], v[m][n][3], h1, l1);
                *reinterpret_cast<uint2*>(&Ah[edge * 136 + feat0]) = make_uint2(h0, h1);
                *reinterpret_cast<uint2*>(&Al[edge * 136 + feat0]) = make_uint2(l0, l1);
            }
        }
        __syncthreads();
    };

    // p0: car = silu(agg@Wup) + xji
    gemm(wh, wl, 2);
    #pragma unroll
    for (int n = 0; n < 2; ++n) {
        const int feat0 = (wv * 2 + n) * 16 + hi4 * 4;
        #pragma unroll
        for (int m = 0; m < 4; ++m) {
            const int edge = r0 + m * 16 + lo4;
            const float4 xv = *reinterpret_cast<const float4*>(&xji[(size_t)edge * 128 + feat0]);
            car[m][n][0] = silu_f(acc[m][n][0]) + xv.x;
            car[m][n][1] = silu_f(acc[m][n][1]) + xv.y;
            car[m][n][2] = silu_f(acc[m][n][2]) + xv.z;
            car[m][n][3] = silu_f(acc[m][n][3]) + xv.w;
        }
    }
    wrA(car);

    auto tphase = [&](const short* Wh, const short* Wl, const float* bias) {
        gemm(Wh, Wl, 4);
        #pragma unroll
        for (int n = 0; n < 2; ++n) {
            const int feat0 = (wv * 2 + n) * 16 + hi4 * 4;
            const float4 bv = *reinterpret_cast<const float4*>(&bias[feat0]);
            #pragma unroll
            for (int m = 0; m < 4; ++m) {
                acc[m][n][0] = silu_f(acc[m][n][0] + bv.x);
                acc[m][n][1] = silu_f(acc[m][n][1] + bv.y);
                acc[m][n][2] = silu_f(acc[m][n][2] + bv.z);
                acc[m][n][3] = silu_f(acc[m][n][3] + bv.w);
            }
        }
        wrA(acc);
    };
    auto cphase = [&](const short* Wh, const short* Wl, const float* bias) {
        gemm(Wh, Wl, 4);
        #pragma unroll
        for (int n = 0; n < 2; ++n) {
            const int feat0 = (wv * 2 + n) * 16 + hi4 * 4;
            const float4 bv = *reinterpret_cast<const float4*>(&bias[feat0]);
            #pragma unroll
            for (int m = 0; m < 4; ++m) {
                car[m][n][0] += silu_f(acc[m][n][0] + bv.x);
                car[m][n][1] += silu_f(acc[m][n][1] + bv.y);
                car[m][n][2] += silu_f(acc[m][n][2] + bv.z);
                car[m][n][3] += silu_f(acc[m][n][3] + bv.w);
            }
        }
        wrA(car);
    };

    tphase(wh + 8192,              wl + 8192,              br + 0 * 128);   // W0
    cphase(wh + 8192 + 16384,      wl + 8192 + 16384,      br + 1 * 128);   // W1

    // p3: car = silu(acc + blin) + xe
    gemm(wh + 8192 + 2 * 16384, wl + 8192 + 2 * 16384, 4);
    #pragma unroll
    for (int n = 0; n < 2; ++n) {
        const int feat0 = (wv * 2 + n) * 16 + hi4 * 4;
        const float4 bv = *reinterpret_cast<const float4*>(&blin[feat0]);
        #pragma unroll
        for (int m = 0; m < 4; ++m) {
            const int edge = r0 + m * 16 + lo4;
            const float4 xv = *reinterpret_cast<const float4*>(&xe[(size_t)edge * 128 + feat0]);
            car[m][n][0] = silu_f(acc[m][n][0] + bv.x) + xv.x;
            car[m][n][1] = silu_f(acc[m][n][1] + bv.y) + xv.y;
            car[m][n][2] = silu_f(acc[m][n][2] + bv.z) + xv.z;
            car[m][n][3] = silu_f(acc[m][n][3] + bv.w) + xv.w;
        }
    }
    wrA(car);

    tphase(wh + 8192 + 3 * 16384, wl + 8192 + 3 * 16384, br + 2 * 128);     // W2
    cphase(wh + 8192 + 4 * 16384, wl + 8192 + 4 * 16384, br + 3 * 128);     // W3
    tphase(wh + 8192 + 5 * 16384, wl + 8192 + 5 * 16384, br + 4 * 128);     // W4

    // p7: out = car + silu(acc + b5)  (float4 stores)
    gemm(wh + 8192 + 6 * 16384, wl + 8192 + 6 * 16384, 4);
    #pragma unroll
    for (int n = 0; n < 2; ++n) {
        const int feat0 = (wv * 2 + n) * 16 + hi4 * 4;
        const float4 bv = *reinterpret_cast<const float4*>(&br[5 * 128 + feat0]);
        #pragma unroll
        for (int m = 0; m < 4; ++m) {
            const int edge = r0 + m * 16 + lo4;
            float4 o = make_float4(car[m][n][0] + silu_f(acc[m][n][0] + bv.x),
                                   car[m][n][1] + silu_f(acc[m][n][1] + bv.y),
                                   car[m][n][2] + silu_f(acc[m][n][2] + bv.z),
                                   car[m][n][3] + silu_f(acc[m][n][3] + bv.w));
            *reinterpret_cast<float4*>(&out[(size_t)edge * 128 + feat0]) = o;
        }
    }
}

// ---------------------------------------------------------------------------
// Node aggregation (CSR over edge_i)
// ---------------------------------------------------------------------------
__global__ __launch_bounds__(256) void k_nodes(
    const int* __restrict__ rs, const int* __restrict__ perm,
    const float* __restrict__ rbf, const float* __restrict__ Wrbf,
    const float* __restrict__ xe, float* __restrict__ nodes)
{
    const int tid = threadIdx.x;
    const int n = blockIdx.x * 2 + (tid >> 7);
    const int c = tid & (H - 1);
    float wr[R];
    #pragma unroll
    for (int i = 0; i < R; ++i) wr[i] = Wrbf[i * H + c];
    float acc = 0.0f;
    const int lo = rs[n], hi = rs[n + 1];
    for (int idx = lo; idx < hi; ++idx) {
        const int e = perm[idx];
        const float* rb = rbf + (size_t)e * R;
        float g = 0.0f;
        #pragma unroll
        for (int i = 0; i < R; ++i) g = fmaf(rb[i], wr[i], g);
        acc = fmaf(g, xe[(size_t)e * H + c], acc);
    }
    nodes[(size_t)n * H + c] = acc;
}

// ---------------------------------------------------------------------------
// Fused output chain (f32)
// ---------------------------------------------------------------------------
__global__ __launch_bounds__(256) void k_outchain(
    const float* __restrict__ nodes, const float* __restrict__ Wup,
    const float* __restrict__ bup, const float* __restrict__ Wlin,
    const float* __restrict__ blin, const float* __restrict__ Wout,
    float* __restrict__ P)
{
    __shared__ float nb[16 * 132];
    __shared__ float hb[16 * 260];
    __shared__ float tbuf[16 * 260];
    __shared__ float red[64 * 16];
    const int tid = threadIdx.x;
    const int n0  = blockIdx.x * 16;
    float4* nb4 = reinterpret_cast<float4*>(nb);
    float4* hb4 = reinterpret_cast<float4*>(hb);
    float4* tb4 = reinterpret_cast<float4*>(tbuf);
    const float4* NG = reinterpret_cast<const float4*>(nodes);

    for (int i = tid; i < 16 * 32; i += 256) {
        int row = i >> 5, kk = i & 31;
        nb4[row * 33 + kk] = NG[(size_t)(n0 + row) * 32 + kk];
    }
    __syncthreads();

    const int cg = tid & 63, rq = tid >> 6, rbase = rq * 4;
    float acc[4][4];
    auto acc_bias = [&](const float* bias) {
        const float4 bv = reinterpret_cast<const float4*>(bias)[cg];
        #pragma unroll
        for (int r = 0; r < 4; ++r) { acc[r][0]=bv.x; acc[r][1]=bv.y; acc[r][2]=bv.z; acc[r][3]=bv.w; }
    };
    auto mm = [&](const float4* A4, const float4* W4, int K4, int AS4) {
        for (int k4 = 0; k4 < K4; ++k4) {
            const float4 wv0 = W4[(k4*4+0)*64 + cg];
            const float4 wv1 = W4[(k4*4+1)*64 + cg];
            const float4 wv2 = W4[(k4*4+2)*64 + cg];
            const float4 wv3 = W4[(k4*4+3)*64 + cg];
            #pragma unroll
            for (int r = 0; r < 4; ++r) {
                const float4 a = A4[(rbase + r) * AS4 + k4];
                acc[r][0]=fmaf(a.x,wv0.x,acc[r][0]); acc[r][1]=fmaf(a.x,wv0.y,acc[r][1]);
                acc[r][2]=fmaf(a.x,wv0.z,acc[r][2]); acc[r][3]=fmaf(a.x,wv0.w,acc[r][3]);
                acc[r][0]=fmaf(a.y,wv1.x,acc[r][0]); acc[r][1]=fmaf(a.y,wv1.y,acc[r][1]);
                acc[r][2]=fmaf(a.y,wv1.z,acc[r][2]); acc[r][3]=fmaf(a.y,wv1.w,acc[r][3]);
                acc[r][0]=fmaf(a.z,wv2.x,acc[r][0]); acc[r][1]=fmaf(a.z,wv2.y,acc[r][1]);
                acc[r][2]=fmaf(a.z,wv2.z,acc[r][2]); acc[r][3]=fmaf(a.z,wv2.w,acc[r][3]);
                acc[r][0]=fmaf(a.w,wv3.x,acc[r][0]); acc[r][1]=fmaf(a.w,wv3.y,acc[r][1]);
                acc[r][2]=fmaf(a.w,wv3.z,acc[r][2]); acc[r][3]=fmaf(a.w,wv3.w,acc[r][3]);
            }
        }
    };

    acc_bias(bup);
    mm(nb4, reinterpret_cast<const float4*>(Wup), 32, 33);
    #pragma unroll
    for (int r = 0; r < 4; ++r) hb4[(rbase + r) * 65 + cg] = make_float4(acc[r][0],acc[r][1],acc[r][2],acc[r][3]);
    __syncthreads();

    acc_bias(blin + 0 * OE);
    mm(hb4, reinterpret_cast<const float4*>(Wlin + 0 * OE * OE), 64, 65);
    #pragma unroll
    for (int r = 0; r < 4; ++r) tb4[(rbase + r) * 65 + cg] = silu4(make_float4(acc[r][0],acc[r][1],acc[r][2],acc[r][3]));
    __syncthreads();

    acc_bias(blin + 1 * OE);
    mm(tb4, reinterpret_cast<const float4*>(Wlin + 1 * OE * OE), 64, 65);
    #pragma unroll
    for (int r = 0; r < 4; ++r) hb4[(rbase + r) * 65 + cg] = silu4(make_float4(acc[r][0],acc[r][1],acc[r][2],acc[r][3]));
    __syncthreads();

    acc_bias(blin + 2 * OE);
    mm(hb4, reinterpret_cast<const float4*>(Wlin + 2 * OE * OE), 64, 65);
    #pragma unroll
    for (int r = 0; r < 4; ++r) tb4[(rbase + r) * 65 + cg] = silu4(make_float4(acc[r][0],acc[r][1],acc[r][2],acc[r][3]));
    __syncthreads();

    {
        const float4 wo = reinterpret_cast<const float4*>(Wout)[cg];
        #pragma unroll
        for (int r = 0; r < 4; ++r) {
            const int row = rbase + r;
            const float4 hv = tb4[row * 65 + cg];
            red[cg * 16 + row] = hv.x * wo.x + hv.y * wo.y + hv.z * wo.z + hv.w * wo.w;
        }
    }
    __syncthreads();
    if (tid < 16) {
        float s = 0.0f;
        for (int c = 0; c < 64; ++c) s += red[c * 16 + tid];
        P[n0 + tid] += s;
    }
}

// ---------------------------------------------------------------------------
extern "C" void kernel_launch(void* const* d_in, const int* in_sizes, int n_in,
                              void* d_out, int out_size, void* d_ws, size_t ws_size,
                              hipStream_t stream)
{
    (void)in_sizes; (void)n_in; (void)out_size; (void)ws_size;

    const float* x       = (const float*)d_in[0];
    const float* dist    = (const float*)d_in[1];
    const float* freq    = (const float*)d_in[2];
    const float* sbf     = (const float*)d_in[3];
    const int*   idx_kj  = (const int*)d_in[4];
    const int*   idx_ji  = (const int*)d_in[5];
    const int*   edge_i  = (const int*)d_in[6];
    const float* Wi_rbf1 = (const float*)d_in[8];
    const float* Wi_rbf2 = (const float*)d_in[9];
    const float* Wi_sbf1 = (const float*)d_in[10];
    const float* Wi_sbf2 = (const float*)d_in[11];
    const float* Wi_kj   = (const float*)d_in[12];
    const float* bi_kj   = (const float*)d_in[13];
    const float* Wi_ji   = (const float*)d_in[14];
    const float* bi_ji   = (const float*)d_in[15];
    const float* Wi_down = (const float*)d_in[16];
    const float* Wi_up   = (const float*)d_in[17];
    const float* Wi_res  = (const float*)d_in[18];
    const float* bi_res  = (const float*)d_in[19];
    const float* Wi_lin  = (const float*)d_in[20];
    const float* bi_lin  = (const float*)d_in[21];
    const float* Wo_rbf  = (const float*)d_in[22];
    const float* Wo_up   = (const float*)d_in[23];
    const float* bo_up   = (const float*)d_in[24];
    const float* Wo_lin  = (const float*)d_in[25];
    const float* bo_lin  = (const float*)d_in[26];
    const float* Wo_out  = (const float*)d_in[27];
    float* P = (float*)d_out;

    // ---- workspace carve-up ----
    float* w      = (float*)d_ws;
    float* rbf    = w;  w += (size_t)E * R;
    float* xeA    = w;  w += (size_t)E * H;
    float* xeB    = w;  w += (size_t)E * H;
    float* xji    = w;  w += (size_t)E * H;
    float* down   = w;  w += (size_t)E * INTD;
    float* agg    = w;  w += (size_t)E * INTD;
    float* tmp0   = w;  w += (size_t)T * BE;
    float* tmp1   = w;  w += (size_t)T * BE;
    float* nodes  = w;  w += (size_t)NN * H;
    int* ip       = (int*)w;
    int* trip_rs  = ip;  ip += E + 1;
    int* trip_cur = ip;  ip += E;
    int* rank_t   = ip;  ip += T;
    int* kjs      = ip;  ip += T;
    int* edge_rs  = ip;  ip += NN + 1;
    int* edge_cur = ip;  ip += NN;
    int* perm_e   = ip;  ip += E;
    int* bsumT    = ip;  ip += 64;
    int* bsumE    = ip;  ip += 64;
    short* wpk_hi = (short*)ip;
    short* wpk_lo = wpk_hi + 2 * PKB;

    // ---- CSR build ----
    hipMemsetAsync(trip_cur, 0, (size_t)E * sizeof(int), stream);
    hipMemsetAsync(edge_cur, 0, (size_t)NN * sizeof(int), stream);
    k_count<<<(T + 255) / 256, 256, 0, stream>>>(idx_ji, T, trip_cur);
    k_count<<<(E + 255) / 256, 256, 0, stream>>>(edge_i, E, edge_cur);
    const int nbT = (E + 2047) / 2048, nbE = (NN + 2047) / 2048;
    k_red<<<nbT, 256, 0, stream>>>(trip_cur, E, bsumT);
    k_scanb<<<1, 64, 0, stream>>>(bsumT, nbT);
    k_fill_rs<<<nbT, 256, 0, stream>>>(trip_cur, E, bsumT, trip_rs, trip_cur);
    k_red<<<nbE, 256, 0, stream>>>(edge_cur, NN, bsumE);
    k_scanb<<<1, 64, 0, stream>>>(bsumE, nbE);
    k_fill_rs<<<nbE, 256, 0, stream>>>(edge_cur, NN, bsumE, edge_rs, edge_cur);
    k_fill_trip<<<(T + 255) / 256, 256, 0, stream>>>(idx_ji, idx_kj, T, trip_cur, kjs, rank_t);
    k_fill<<<(E + 255) / 256, 256, 0, stream>>>(edge_i, E, edge_cur, perm_e);

    hipMemsetAsync(d_out, 0, (size_t)NN * sizeof(float), stream);
    k_rbf<<<(E + 255) / 256, 256, 0, stream>>>(dist, freq, rbf);
    k_pack<<<(2 * PKB + 255) / 256, 256, 0, stream>>>(Wi_ji, Wi_kj, Wi_down,
                                                      Wi_up, Wi_res, Wi_lin,
                                                      wpk_hi, wpk_lo);
    k_sbfproj2<<<T / 32, 256, 0, stream>>>(sbf, Wi_sbf1, Wi_sbf1 + (size_t)SR * BE,
                                           rank_t, tmp0, tmp1);

    auto out_block = [&](int b, const float* xe) {
        k_nodes<<<NN / 2, 256, 0, stream>>>(edge_rs, perm_e, rbf,
                                            Wo_rbf + (size_t)b * R * H, xe, nodes);
        k_outchain<<<NN / 16, 256, 0, stream>>>(nodes,
                                                Wo_up + (size_t)b * H * OE,
                                                bo_up + (size_t)b * OE,
                                                Wo_lin + (size_t)b * 3 * OE * OE,
                                                bo_lin + (size_t)b * 3 * OE,
                                                Wo_out + (size_t)b * OE, P);
    };

    const int gE64 = E / 64;
    auto interact = [&](int b, const float* xe, const float* tmp, float* out) {
        k_front_mfma<<<gE64, 256, 0, stream>>>(xe, rbf,
                                               wpk_hi + (size_t)b * PKB,
                                               wpk_lo + (size_t)b * PKB,
                                               bi_ji + (size_t)b * H,
                                               bi_kj + (size_t)b * H,
                                               Wi_rbf1 + (size_t)b * R * BE,
                                               Wi_rbf2 + (size_t)b * BE * H,
                                               xji, down);
        k_agg<<<E / 4, 256, 0, stream>>>(trip_rs, kjs, tmp, down,
                                         Wi_sbf2 + (size_t)b * BE * INTD, agg);
        k_tail_mfma<<<gE64, 256, 0, stream>>>(agg, xji, xe,
                                              wpk_hi + (size_t)b * PKB + TAILO,
                                              wpk_lo + (size_t)b * PKB + TAILO,
                                              bi_res + (size_t)b * 3 * 2 * H,
                                              bi_lin + (size_t)b * H, out);
    };

    out_block(0, x);
    interact(0, x, tmp0, xeB);
    out_block(1, xeB);
    interact(1, xeB, tmp1, xeA);
    out_block(2, xeA);
}